// Round 5
// baseline (3416.171 us; speedup 1.0000x reference)
//
#include <hip/hip_runtime.h>

// ---------------------------------------------------------------------------
// GAT(2 layers) + NFM + projection for MI355X.
// Pipeline:
//   CSR build (hist -> scan -> scatter)            [once per call]
//   L1: GEMM x@W0 -> fvec -> edge softmax -> agg   -> H1
//   L2: GEMM H1@W1 -> fvec -> edge softmax -> agg  -> H2
//   NFM dual-GEMM on x -> nfm
//   proj: [H2|nfm]@P + b -> out
// ---------------------------------------------------------------------------

__device__ __forceinline__ int wave_prefix_incl(int v) {
  int lane = threadIdx.x & 63;
#pragma unroll
  for (int d = 1; d < 64; d <<= 1) {
    int n = __shfl_up(v, d);
    if (lane >= d) v += n;
  }
  return v;
}

// ------------------------------ CSR build ---------------------------------

__global__ void k_hist(const int* __restrict__ src, int* __restrict__ cnt, int E) {
  int e = blockIdx.x * blockDim.x + threadIdx.x;
  if (e < E) atomicAdd(&cnt[src[e]], 1);
}

// 256 threads, each handles 2 consecutive elements -> chunk of 512
__global__ void k_scan1(const int* __restrict__ cnt, int* __restrict__ row_ptr,
                        int* __restrict__ partials, int N) {
  int t = threadIdx.x;
  int base = blockIdx.x * 512 + t * 2;
  int e0 = (base < N) ? cnt[base] : 0;
  int e1 = (base + 1 < N) ? cnt[base + 1] : 0;
  int v = e0 + e1;
  int lane = t & 63, wid = t >> 6;
  int incl = wave_prefix_incl(v);
  __shared__ int wsum[4];
  if (lane == 63) wsum[wid] = incl;
  __syncthreads();
  int off = 0;
#pragma unroll
  for (int i = 0; i < 4; ++i)
    if (i < wid) off += wsum[i];
  incl += off;
  int excl = incl - v;
  if (base < N) row_ptr[base] = excl;
  if (base + 1 < N) row_ptr[base + 1] = excl + e0;
  if (t == 255) partials[blockIdx.x] = incl;
}

// single block scans the partials (P <= 256)
__global__ void k_scan2(int* partials, int P) {
  int t = threadIdx.x;
  int v = (t < P) ? partials[t] : 0;
  int lane = t & 63, wid = t >> 6;
  int incl = wave_prefix_incl(v);
  __shared__ int wsum[4];
  if (lane == 63) wsum[wid] = incl;
  __syncthreads();
  int off = 0;
#pragma unroll
  for (int i = 0; i < 4; ++i)
    if (i < wid) off += wsum[i];
  incl += off;
  if (t < P) partials[t] = incl - v; // exclusive
}

__global__ void k_scan3(int* __restrict__ row_ptr, int* __restrict__ cursor,
                        const int* __restrict__ partials, int N, int E) {
  int i = blockIdx.x * blockDim.x + threadIdx.x;
  if (i < N) {
    int v = row_ptr[i] + partials[i >> 9];
    row_ptr[i] = v;
    cursor[i] = v;
  }
  if (i == 0) row_ptr[N] = E;
}

__global__ void k_scatter(const int* __restrict__ src, int* __restrict__ cursor,
                          int* __restrict__ eid, int E) {
  int e = blockIdx.x * blockDim.x + threadIdx.x;
  if (e < E) {
    int p = atomicAdd(&cursor[src[e]], 1);
    eid[p] = e;
  }
}

// ------------------------------ fp32 GEMM ---------------------------------
// C[M,N] = A[M,K] @ B[K,N].  BM=128 BN=64 BK=16, 256 thr, 8x4 micro-tile.
// Requires N % 64 == 0, K % 16 == 0 (true for all uses).

template <int BM, int BN, int BK>
__global__ __launch_bounds__(256) void k_gemm(const float* __restrict__ A,
                                              const float* __restrict__ B,
                                              float* __restrict__ C, int M, int N,
                                              int K) {
  __shared__ float As[BK][BM];
  __shared__ float Bs[BK][BN];
  int t = threadIdx.x;
  int bm0 = blockIdx.x * BM, bn0 = blockIdx.y * BN;
  int tr = t >> 4, tc = t & 15;
  int row0 = tr * 8, col0 = tc * 4;
  float acc[8][4] = {};
  for (int k0 = 0; k0 < K; k0 += BK) {
#pragma unroll
    for (int i = 0; i < 2; ++i) {
      int s = t + i * 256;
      int ar = s >> 2, akq = (s & 3) * 4;
      int grow = bm0 + ar;
      if (grow >= M) grow = M - 1;
      const float4 av =
          *reinterpret_cast<const float4*>(&A[(size_t)grow * K + k0 + akq]);
      As[akq + 0][ar] = av.x;
      As[akq + 1][ar] = av.y;
      As[akq + 2][ar] = av.z;
      As[akq + 3][ar] = av.w;
    }
    {
      int br = t >> 4, bc = (t & 15) * 4;
      const float4 bv =
          *reinterpret_cast<const float4*>(&B[(size_t)(k0 + br) * N + bn0 + bc]);
      *reinterpret_cast<float4*>(&Bs[br][bc]) = bv;
    }
    __syncthreads();
#pragma unroll
    for (int k = 0; k < BK; ++k) {
      float a0[8], b0[4];
      *reinterpret_cast<float4*>(&a0[0]) =
          *reinterpret_cast<const float4*>(&As[k][row0]);
      *reinterpret_cast<float4*>(&a0[4]) =
          *reinterpret_cast<const float4*>(&As[k][row0 + 4]);
      *reinterpret_cast<float4*>(&b0[0]) =
          *reinterpret_cast<const float4*>(&Bs[k][col0]);
#pragma unroll
      for (int i = 0; i < 8; ++i)
#pragma unroll
        for (int j = 0; j < 4; ++j) acc[i][j] = fmaf(a0[i], b0[j], acc[i][j]);
    }
    __syncthreads();
  }
#pragma unroll
  for (int i = 0; i < 8; ++i) {
    int grow = bm0 + row0 + i;
    if (grow < M) {
      float4 v = {acc[i][0], acc[i][1], acc[i][2], acc[i][3]};
      *reinterpret_cast<float4*>(&C[(size_t)grow * N + bn0 + col0]) = v;
    }
  }
}

// NFM: summed = X@Emb, sq = X@Emb^2, out = 0.5*(summed^2 - sq).  N fixed 64.
__global__ __launch_bounds__(256) void k_nfm(const float* __restrict__ X,
                                             const float* __restrict__ Emb,
                                             float* __restrict__ out, int M,
                                             int K) {
  const int BM = 128, BN = 64, BK = 16;
  __shared__ float As[BK][BM];
  __shared__ float Bs[BK][BN];
  int t = threadIdx.x;
  int bm0 = blockIdx.x * BM;
  int tr = t >> 4, tc = t & 15;
  int row0 = tr * 8, col0 = tc * 4;
  float accS[8][4] = {}, accQ[8][4] = {};
  for (int k0 = 0; k0 < K; k0 += BK) {
#pragma unroll
    for (int i = 0; i < 2; ++i) {
      int s = t + i * 256;
      int ar = s >> 2, akq = (s & 3) * 4;
      int grow = bm0 + ar;
      if (grow >= M) grow = M - 1;
      const float4 av =
          *reinterpret_cast<const float4*>(&X[(size_t)grow * K + k0 + akq]);
      As[akq + 0][ar] = av.x;
      As[akq + 1][ar] = av.y;
      As[akq + 2][ar] = av.z;
      As[akq + 3][ar] = av.w;
    }
    {
      int br = t >> 4, bc = (t & 15) * 4;
      const float4 bv =
          *reinterpret_cast<const float4*>(&Emb[(size_t)(k0 + br) * BN + bc]);
      *reinterpret_cast<float4*>(&Bs[br][bc]) = bv;
    }
    __syncthreads();
#pragma unroll
    for (int k = 0; k < BK; ++k) {
      float a0[8], b0[4], bq[4];
      *reinterpret_cast<float4*>(&a0[0]) =
          *reinterpret_cast<const float4*>(&As[k][row0]);
      *reinterpret_cast<float4*>(&a0[4]) =
          *reinterpret_cast<const float4*>(&As[k][row0 + 4]);
      *reinterpret_cast<float4*>(&b0[0]) =
          *reinterpret_cast<const float4*>(&Bs[k][col0]);
#pragma unroll
      for (int j = 0; j < 4; ++j) bq[j] = b0[j] * b0[j];
#pragma unroll
      for (int i = 0; i < 8; ++i)
#pragma unroll
        for (int j = 0; j < 4; ++j) {
          accS[i][j] = fmaf(a0[i], b0[j], accS[i][j]);
          accQ[i][j] = fmaf(a0[i], bq[j], accQ[i][j]);
        }
    }
    __syncthreads();
  }
#pragma unroll
  for (int i = 0; i < 8; ++i) {
    int grow = bm0 + row0 + i;
    if (grow < M) {
      float4 v;
      v.x = 0.5f * (accS[i][0] * accS[i][0] - accQ[i][0]);
      v.y = 0.5f * (accS[i][1] * accS[i][1] - accQ[i][1]);
      v.z = 0.5f * (accS[i][2] * accS[i][2] - accQ[i][2]);
      v.w = 0.5f * (accS[i][3] * accS[i][3] - accQ[i][3]);
      *reinterpret_cast<float4*>(&out[(size_t)grow * 64 + col0]) = v;
    }
  }
}

// ------------------------- GAT edge machinery ------------------------------

// f1 = Hw @ va, f2 = Hw @ vb, one wave per node
template <int D>
__global__ __launch_bounds__(256) void k_fvec(const float* __restrict__ Hw,
                                              const float* __restrict__ va,
                                              const float* __restrict__ vb,
                                              float* __restrict__ f1,
                                              float* __restrict__ f2, int M) {
  int wid = threadIdx.x >> 6, lane = threadIdx.x & 63;
  int i = blockIdx.x * 4 + wid;
  if (i >= M) return;
  const float* row = Hw + (size_t)i * D;
  float s1, s2;
  if (D == 256) {
    float4 h = *reinterpret_cast<const float4*>(&row[lane * 4]);
    float4 a = *reinterpret_cast<const float4*>(&va[lane * 4]);
    float4 b = *reinterpret_cast<const float4*>(&vb[lane * 4]);
    s1 = h.x * a.x + h.y * a.y + h.z * a.z + h.w * a.w;
    s2 = h.x * b.x + h.y * b.y + h.z * b.z + h.w * b.w;
  } else {
    float2 h = *reinterpret_cast<const float2*>(&row[lane * 2]);
    float2 a = *reinterpret_cast<const float2*>(&va[lane * 2]);
    float2 b = *reinterpret_cast<const float2*>(&vb[lane * 2]);
    s1 = h.x * a.x + h.y * a.y;
    s2 = h.x * b.x + h.y * b.y;
  }
#pragma unroll
  for (int d = 32; d; d >>= 1) {
    s1 += __shfl_down(s1, d);
    s2 += __shfl_down(s2, d);
  }
  if (lane == 0) {
    f1[i] = s1;
    f2[i] = s2;
  }
}

// s = sigmoid(a*(f1[src]+f2[dst])); att<-s; m[src] = max(m, s) (s>0 so int-bits OK)
__global__ void k_edge_s(const float* __restrict__ aval, const int* __restrict__ src,
                         const int* __restrict__ dst, const float* __restrict__ f1,
                         const float* __restrict__ f2, float* __restrict__ att,
                         float* __restrict__ m, int E) {
  int e = blockIdx.x * blockDim.x + threadIdx.x;
  if (e >= E) return;
  float x = aval[e] * (f1[src[e]] + f2[dst[e]]);
  float s = 1.0f / (1.0f + __expf(-x));
  att[e] = s;
  atomicMax((int*)&m[src[e]], __float_as_int(s));
}

// att <- exp(att - m[src]); denom[src] += att
__global__ void k_edge_exp(const int* __restrict__ src, const float* __restrict__ m,
                           float* __restrict__ att, float* __restrict__ denom,
                           int E) {
  int e = blockIdx.x * blockDim.x + threadIdx.x;
  if (e >= E) return;
  float ev = __expf(att[e] - m[src[e]]);
  att[e] = ev;
  atomicAdd(&denom[src[e]], ev);
}

// out[i] = (sum over edges of node i: att_e * Hw[dst_e]) / denom[i]
template <int D>
__global__ __launch_bounds__(256) void k_agg(const float* __restrict__ Hw,
                                             const float* __restrict__ att,
                                             const int* __restrict__ row_ptr,
                                             const int* __restrict__ eid,
                                             const int* __restrict__ dst,
                                             const float* __restrict__ denom,
                                             float* __restrict__ out, int M) {
  int wid = threadIdx.x >> 6, lane = threadIdx.x & 63;
  int i = blockIdx.x * 4 + wid;
  if (i >= M) return;
  int p0 = __builtin_amdgcn_readfirstlane(row_ptr[i]);
  int p1 = __builtin_amdgcn_readfirstlane(row_ptr[i + 1]);
  if (D == 256) {
    float4 acc = {0.f, 0.f, 0.f, 0.f};
    for (int p = p0; p < p1; ++p) {
      int e = eid[p];
      float w = att[e];
      int j = dst[e];
      float4 h = *reinterpret_cast<const float4*>(&Hw[(size_t)j * 256 + lane * 4]);
      acc.x = fmaf(w, h.x, acc.x);
      acc.y = fmaf(w, h.y, acc.y);
      acc.z = fmaf(w, h.z, acc.z);
      acc.w = fmaf(w, h.w, acc.w);
    }
    float inv = (p1 > p0) ? 1.0f / denom[i] : 0.0f;
    float4 o = {acc.x * inv, acc.y * inv, acc.z * inv, acc.w * inv};
    *reinterpret_cast<float4*>(&out[(size_t)i * 256 + lane * 4]) = o;
  } else {
    float2 acc = {0.f, 0.f};
    for (int p = p0; p < p1; ++p) {
      int e = eid[p];
      float w = att[e];
      int j = dst[e];
      float2 h = *reinterpret_cast<const float2*>(&Hw[(size_t)j * 128 + lane * 2]);
      acc.x = fmaf(w, h.x, acc.x);
      acc.y = fmaf(w, h.y, acc.y);
    }
    float inv = (p1 > p0) ? 1.0f / denom[i] : 0.0f;
    float2 o = {acc.x * inv, acc.y * inv};
    *reinterpret_cast<float2*>(&out[(size_t)i * 128 + lane * 2]) = o;
  }
}

// ----------------------------- projection ----------------------------------
// out[i,:] = [H2[i,:128] | nfm[i,:64]] @ P[192,64] + b
__global__ __launch_bounds__(256) void k_proj(const float* __restrict__ H2,
                                              const float* __restrict__ nfm,
                                              const float* __restrict__ P,
                                              const float* __restrict__ b,
                                              float* __restrict__ out, int M) {
  __shared__ float Ps[192 * 64];
  __shared__ float bs[64];
  int t = threadIdx.x;
  for (int idx = t; idx < 192 * 64; idx += 256) Ps[idx] = P[idx];
  if (t < 64) bs[t] = b[t];
  __syncthreads();
  int wid = t >> 6, lane = t & 63;
  for (int i = blockIdx.x * 4 + wid; i < M; i += gridDim.x * 4) {
    float h0 = H2[(size_t)i * 128 + lane];
    float h1 = H2[(size_t)i * 128 + 64 + lane];
    float fm = nfm[(size_t)i * 64 + lane];
    float acc = bs[lane];
#pragma unroll
    for (int k = 0; k < 64; ++k) acc = fmaf(__shfl(h0, k), Ps[k * 64 + lane], acc);
#pragma unroll
    for (int k = 0; k < 64; ++k)
      acc = fmaf(__shfl(h1, k), Ps[(64 + k) * 64 + lane], acc);
#pragma unroll
    for (int k = 0; k < 64; ++k)
      acc = fmaf(__shfl(fm, k), Ps[(128 + k) * 64 + lane], acc);
    out[(size_t)i * 64 + lane] = acc;
  }
}

// ------------------------------ launcher -----------------------------------

extern "C" void kernel_launch(void* const* d_in, const int* in_sizes, int n_in,
                              void* d_out, int out_size, void* d_ws, size_t ws_size,
                              hipStream_t stream) {
  (void)n_in;
  (void)out_size;
  const float* x = (const float*)d_in[0];
  const float* aval = (const float*)d_in[1];
  const float* W0 = (const float*)d_in[2];
  const float* W1 = (const float*)d_in[3];
  const float* v00 = (const float*)d_in[4];
  const float* v01 = (const float*)d_in[5];
  const float* v10 = (const float*)d_in[6];
  const float* v11 = (const float*)d_in[7];
  const float* fme = (const float*)d_in[8];
  const float* pW = (const float*)d_in[9];
  const float* pb = (const float*)d_in[10];
  const int* esrc = (const int*)d_in[11];
  const int* edst = (const int*)d_in[12];
  const int N = in_sizes[0] / 512;
  const int E = in_sizes[1];
  float* out = (float*)d_out;

  char* w = (char*)d_ws;
  size_t off = 0;
  auto alloc = [&](size_t bytes) -> char* {
    char* p = w + off;
    off += (bytes + 255) & ~(size_t)255;
    return p;
  };
  float* Hw0 = (float*)alloc((size_t)N * 256 * 4); // later: Hw1 | H2
  float* H1 = (float*)alloc((size_t)N * 256 * 4);
  float* nfm = (float*)alloc((size_t)N * 64 * 4);
  float* f1 = (float*)alloc((size_t)N * 4);
  float* f2 = (float*)alloc((size_t)N * 4);
  float* mbuf = (float*)alloc((size_t)N * 4);
  float* dnm = (float*)alloc((size_t)N * 4);
  float* att = (float*)alloc((size_t)E * 4);
  int* cnt = (int*)alloc((size_t)N * 4);
  int* rp = (int*)alloc((size_t)(N + 1) * 4);
  int* cur = (int*)alloc((size_t)N * 4);
  int* eid = (int*)alloc((size_t)E * 4);
  int* part = (int*)alloc(4096);
  if (off > ws_size) return; // workspace too small: fail loudly via validation

  float* Hw1 = Hw0;                    // N x 128 (Hw0 dead by then)
  float* H2 = Hw0 + (size_t)N * 128;   // N x 128, disjoint from Hw1

  const int TPB = 256;
  int egrid = (E + TPB - 1) / TPB;
  int ngrid4 = (N + 3) / 4;
  int P = (N + 511) / 512;

  // ---- CSR build ----
  hipMemsetAsync(cnt, 0, (size_t)N * 4, stream);
  k_hist<<<egrid, TPB, 0, stream>>>(esrc, cnt, E);
  k_scan1<<<P, TPB, 0, stream>>>(cnt, rp, part, N);
  k_scan2<<<1, TPB, 0, stream>>>(part, P);
  k_scan3<<<(N + TPB) / TPB, TPB, 0, stream>>>(rp, cur, part, N, E);
  k_scatter<<<egrid, TPB, 0, stream>>>(esrc, cur, eid, E);

  // ---- Layer 1 (d=256) ----
  {
    dim3 g((N + 127) / 128, 256 / 64);
    k_gemm<128, 64, 16><<<g, TPB, 0, stream>>>(x, W0, Hw0, N, 256, 512);
  }
  k_fvec<256><<<ngrid4, TPB, 0, stream>>>(Hw0, v00, v01, f1, f2, N);
  hipMemsetAsync(mbuf, 0, (size_t)N * 4, stream);
  hipMemsetAsync(dnm, 0, (size_t)N * 4, stream);
  k_edge_s<<<egrid, TPB, 0, stream>>>(aval, esrc, edst, f1, f2, att, mbuf, E);
  k_edge_exp<<<egrid, TPB, 0, stream>>>(esrc, mbuf, att, dnm, E);
  k_agg<256><<<ngrid4, TPB, 0, stream>>>(Hw0, att, rp, eid, edst, dnm, H1, N);

  // ---- Layer 2 (d=128) ----
  {
    dim3 g((N + 127) / 128, 128 / 64);
    k_gemm<128, 64, 16><<<g, TPB, 0, stream>>>(H1, W1, Hw1, N, 128, 256);
  }
  k_fvec<128><<<ngrid4, TPB, 0, stream>>>(Hw1, v10, v11, f1, f2, N);
  hipMemsetAsync(mbuf, 0, (size_t)N * 4, stream);
  hipMemsetAsync(dnm, 0, (size_t)N * 4, stream);
  k_edge_s<<<egrid, TPB, 0, stream>>>(aval, esrc, edst, f1, f2, att, mbuf, E);
  k_edge_exp<<<egrid, TPB, 0, stream>>>(esrc, mbuf, att, dnm, E);
  k_agg<128><<<ngrid4, TPB, 0, stream>>>(Hw1, att, rp, eid, edst, dnm, H2, N);

  // ---- NFM ----
  k_nfm<<<(N + 127) / 128, TPB, 0, stream>>>(x, fme, nfm, N, 512);

  // ---- projection ----
  k_proj<<<1024, TPB, 0, stream>>>(H2, nfm, pW, pb, out, N);
}

// Round 7
// 2873.222 us; speedup vs baseline: 1.1890x; 1.1890x over previous
//
#include <hip/hip_runtime.h>

// ---------------------------------------------------------------------------
// GAT(2 layers) + NFM + projection for MI355X.
// Pipeline:
//   CSR build (hist -> scan -> scatter)            [once per call]
//   L1: GEMM x@W0 -> fvec -> edge softmax -> agg   -> H1
//   L2: GEMM H1@W1 -> fvec -> edge softmax -> agg  -> Hcat[:, :128]
//   NFM dual-GEMM on x -> Hcat[:, 128:192]   (Hcat aliases dead H1 buffer)
//   proj GEMM: Hcat[N,192] @ P[192,64] + b -> out
// R5: k_proj shuffle-broadcast was latency-bound (627us, VALUBusy 7%,
//     occ 12%) -> replaced with tiled GEMM over assembled Hcat.
// ---------------------------------------------------------------------------

__device__ __forceinline__ int wave_prefix_incl(int v) {
  int lane = threadIdx.x & 63;
#pragma unroll
  for (int d = 1; d < 64; d <<= 1) {
    int n = __shfl_up(v, d);
    if (lane >= d) v += n;
  }
  return v;
}

// ------------------------------ CSR build ---------------------------------

__global__ void k_hist(const int* __restrict__ src, int* __restrict__ cnt, int E) {
  int e = blockIdx.x * blockDim.x + threadIdx.x;
  if (e < E) atomicAdd(&cnt[src[e]], 1);
}

// 256 threads, each handles 2 consecutive elements -> chunk of 512
__global__ void k_scan1(const int* __restrict__ cnt, int* __restrict__ row_ptr,
                        int* __restrict__ partials, int N) {
  int t = threadIdx.x;
  int base = blockIdx.x * 512 + t * 2;
  int e0 = (base < N) ? cnt[base] : 0;
  int e1 = (base + 1 < N) ? cnt[base + 1] : 0;
  int v = e0 + e1;
  int lane = t & 63, wid = t >> 6;
  int incl = wave_prefix_incl(v);
  __shared__ int wsum[4];
  if (lane == 63) wsum[wid] = incl;
  __syncthreads();
  int off = 0;
#pragma unroll
  for (int i = 0; i < 4; ++i)
    if (i < wid) off += wsum[i];
  incl += off;
  int excl = incl - v;
  if (base < N) row_ptr[base] = excl;
  if (base + 1 < N) row_ptr[base + 1] = excl + e0;
  if (t == 255) partials[blockIdx.x] = incl;
}

// single block scans the partials (P <= 256)
__global__ void k_scan2(int* partials, int P) {
  int t = threadIdx.x;
  int v = (t < P) ? partials[t] : 0;
  int lane = t & 63, wid = t >> 6;
  int incl = wave_prefix_incl(v);
  __shared__ int wsum[4];
  if (lane == 63) wsum[wid] = incl;
  __syncthreads();
  int off = 0;
#pragma unroll
  for (int i = 0; i < 4; ++i)
    if (i < wid) off += wsum[i];
  incl += off;
  if (t < P) partials[t] = incl - v; // exclusive
}

__global__ void k_scan3(int* __restrict__ row_ptr, int* __restrict__ cursor,
                        const int* __restrict__ partials, int N, int E) {
  int i = blockIdx.x * blockDim.x + threadIdx.x;
  if (i < N) {
    int v = row_ptr[i] + partials[i >> 9];
    row_ptr[i] = v;
    cursor[i] = v;
  }
  if (i == 0) row_ptr[N] = E;
}

__global__ void k_scatter(const int* __restrict__ src, int* __restrict__ cursor,
                          int* __restrict__ eid, int E) {
  int e = blockIdx.x * blockDim.x + threadIdx.x;
  if (e < E) {
    int p = atomicAdd(&cursor[src[e]], 1);
    eid[p] = e;
  }
}

// ------------------------------ fp32 GEMM ---------------------------------
// C[M,N] = A[M,K] @ B[K,N].  BM=128 BN=64 BK=16, 256 thr, 8x4 micro-tile.
// Requires N % 64 == 0, K % 16 == 0 (true for all uses).

template <int BM, int BN, int BK>
__global__ __launch_bounds__(256) void k_gemm(const float* __restrict__ A,
                                              const float* __restrict__ B,
                                              float* __restrict__ C, int M, int N,
                                              int K) {
  __shared__ float As[BK][BM];
  __shared__ float Bs[BK][BN];
  int t = threadIdx.x;
  int bm0 = blockIdx.x * BM, bn0 = blockIdx.y * BN;
  int tr = t >> 4, tc = t & 15;
  int row0 = tr * 8, col0 = tc * 4;
  float acc[8][4] = {};
  for (int k0 = 0; k0 < K; k0 += BK) {
#pragma unroll
    for (int i = 0; i < 2; ++i) {
      int s = t + i * 256;
      int ar = s >> 2, akq = (s & 3) * 4;
      int grow = bm0 + ar;
      if (grow >= M) grow = M - 1;
      const float4 av =
          *reinterpret_cast<const float4*>(&A[(size_t)grow * K + k0 + akq]);
      As[akq + 0][ar] = av.x;
      As[akq + 1][ar] = av.y;
      As[akq + 2][ar] = av.z;
      As[akq + 3][ar] = av.w;
    }
    {
      int br = t >> 4, bc = (t & 15) * 4;
      const float4 bv =
          *reinterpret_cast<const float4*>(&B[(size_t)(k0 + br) * N + bn0 + bc]);
      *reinterpret_cast<float4*>(&Bs[br][bc]) = bv;
    }
    __syncthreads();
#pragma unroll
    for (int k = 0; k < BK; ++k) {
      float a0[8], b0[4];
      *reinterpret_cast<float4*>(&a0[0]) =
          *reinterpret_cast<const float4*>(&As[k][row0]);
      *reinterpret_cast<float4*>(&a0[4]) =
          *reinterpret_cast<const float4*>(&As[k][row0 + 4]);
      *reinterpret_cast<float4*>(&b0[0]) =
          *reinterpret_cast<const float4*>(&Bs[k][col0]);
#pragma unroll
      for (int i = 0; i < 8; ++i)
#pragma unroll
        for (int j = 0; j < 4; ++j) acc[i][j] = fmaf(a0[i], b0[j], acc[i][j]);
    }
    __syncthreads();
  }
#pragma unroll
  for (int i = 0; i < 8; ++i) {
    int grow = bm0 + row0 + i;
    if (grow < M) {
      float4 v = {acc[i][0], acc[i][1], acc[i][2], acc[i][3]};
      *reinterpret_cast<float4*>(&C[(size_t)grow * N + bn0 + col0]) = v;
    }
  }
}

// Same as k_gemm but adds a bias vector over N in the epilogue (projection).
template <int BM, int BN, int BK>
__global__ __launch_bounds__(256) void k_gemm_bias(const float* __restrict__ A,
                                                   const float* __restrict__ B,
                                                   const float* __restrict__ bias,
                                                   float* __restrict__ C, int M,
                                                   int N, int K) {
  __shared__ float As[BK][BM];
  __shared__ float Bs[BK][BN];
  int t = threadIdx.x;
  int bm0 = blockIdx.x * BM, bn0 = blockIdx.y * BN;
  int tr = t >> 4, tc = t & 15;
  int row0 = tr * 8, col0 = tc * 4;
  float acc[8][4] = {};
  for (int k0 = 0; k0 < K; k0 += BK) {
#pragma unroll
    for (int i = 0; i < 2; ++i) {
      int s = t + i * 256;
      int ar = s >> 2, akq = (s & 3) * 4;
      int grow = bm0 + ar;
      if (grow >= M) grow = M - 1;
      const float4 av =
          *reinterpret_cast<const float4*>(&A[(size_t)grow * K + k0 + akq]);
      As[akq + 0][ar] = av.x;
      As[akq + 1][ar] = av.y;
      As[akq + 2][ar] = av.z;
      As[akq + 3][ar] = av.w;
    }
    {
      int br = t >> 4, bc = (t & 15) * 4;
      const float4 bv =
          *reinterpret_cast<const float4*>(&B[(size_t)(k0 + br) * N + bn0 + bc]);
      *reinterpret_cast<float4*>(&Bs[br][bc]) = bv;
    }
    __syncthreads();
#pragma unroll
    for (int k = 0; k < BK; ++k) {
      float a0[8], b0[4];
      *reinterpret_cast<float4*>(&a0[0]) =
          *reinterpret_cast<const float4*>(&As[k][row0]);
      *reinterpret_cast<float4*>(&a0[4]) =
          *reinterpret_cast<const float4*>(&As[k][row0 + 4]);
      *reinterpret_cast<float4*>(&b0[0]) =
          *reinterpret_cast<const float4*>(&Bs[k][col0]);
#pragma unroll
      for (int i = 0; i < 8; ++i)
#pragma unroll
        for (int j = 0; j < 4; ++j) acc[i][j] = fmaf(a0[i], b0[j], acc[i][j]);
    }
    __syncthreads();
  }
  const float4 bv = *reinterpret_cast<const float4*>(&bias[bn0 + col0]);
#pragma unroll
  for (int i = 0; i < 8; ++i) {
    int grow = bm0 + row0 + i;
    if (grow < M) {
      float4 v = {acc[i][0] + bv.x, acc[i][1] + bv.y, acc[i][2] + bv.z,
                  acc[i][3] + bv.w};
      *reinterpret_cast<float4*>(&C[(size_t)grow * N + bn0 + col0]) = v;
    }
  }
}

// NFM: summed = X@Emb, sq = X@Emb^2, out[i, col] (row stride ldo) =
// 0.5*(summed^2 - sq).  Emb is [K,64].
__global__ __launch_bounds__(256) void k_nfm(const float* __restrict__ X,
                                             const float* __restrict__ Emb,
                                             float* __restrict__ out, int M,
                                             int K, int ldo) {
  const int BM = 128, BN = 64, BK = 16;
  __shared__ float As[BK][BM];
  __shared__ float Bs[BK][BN];
  int t = threadIdx.x;
  int bm0 = blockIdx.x * BM;
  int tr = t >> 4, tc = t & 15;
  int row0 = tr * 8, col0 = tc * 4;
  float accS[8][4] = {}, accQ[8][4] = {};
  for (int k0 = 0; k0 < K; k0 += BK) {
#pragma unroll
    for (int i = 0; i < 2; ++i) {
      int s = t + i * 256;
      int ar = s >> 2, akq = (s & 3) * 4;
      int grow = bm0 + ar;
      if (grow >= M) grow = M - 1;
      const float4 av =
          *reinterpret_cast<const float4*>(&X[(size_t)grow * K + k0 + akq]);
      As[akq + 0][ar] = av.x;
      As[akq + 1][ar] = av.y;
      As[akq + 2][ar] = av.z;
      As[akq + 3][ar] = av.w;
    }
    {
      int br = t >> 4, bc = (t & 15) * 4;
      const float4 bv =
          *reinterpret_cast<const float4*>(&Emb[(size_t)(k0 + br) * BN + bc]);
      *reinterpret_cast<float4*>(&Bs[br][bc]) = bv;
    }
    __syncthreads();
#pragma unroll
    for (int k = 0; k < BK; ++k) {
      float a0[8], b0[4], bq[4];
      *reinterpret_cast<float4*>(&a0[0]) =
          *reinterpret_cast<const float4*>(&As[k][row0]);
      *reinterpret_cast<float4*>(&a0[4]) =
          *reinterpret_cast<const float4*>(&As[k][row0 + 4]);
      *reinterpret_cast<float4*>(&b0[0]) =
          *reinterpret_cast<const float4*>(&Bs[k][col0]);
#pragma unroll
      for (int j = 0; j < 4; ++j) bq[j] = b0[j] * b0[j];
#pragma unroll
      for (int i = 0; i < 8; ++i)
#pragma unroll
        for (int j = 0; j < 4; ++j) {
          accS[i][j] = fmaf(a0[i], b0[j], accS[i][j]);
          accQ[i][j] = fmaf(a0[i], bq[j], accQ[i][j]);
        }
    }
    __syncthreads();
  }
#pragma unroll
  for (int i = 0; i < 8; ++i) {
    int grow = bm0 + row0 + i;
    if (grow < M) {
      float4 v;
      v.x = 0.5f * (accS[i][0] * accS[i][0] - accQ[i][0]);
      v.y = 0.5f * (accS[i][1] * accS[i][1] - accQ[i][1]);
      v.z = 0.5f * (accS[i][2] * accS[i][2] - accQ[i][2]);
      v.w = 0.5f * (accS[i][3] * accS[i][3] - accQ[i][3]);
      *reinterpret_cast<float4*>(&out[(size_t)grow * ldo + col0]) = v;
    }
  }
}

// ------------------------- GAT edge machinery ------------------------------

// f1 = Hw @ va, f2 = Hw @ vb, one wave per node
template <int D>
__global__ __launch_bounds__(256) void k_fvec(const float* __restrict__ Hw,
                                              const float* __restrict__ va,
                                              const float* __restrict__ vb,
                                              float* __restrict__ f1,
                                              float* __restrict__ f2, int M) {
  int wid = threadIdx.x >> 6, lane = threadIdx.x & 63;
  int i = blockIdx.x * 4 + wid;
  if (i >= M) return;
  const float* row = Hw + (size_t)i * D;
  float s1, s2;
  if (D == 256) {
    float4 h = *reinterpret_cast<const float4*>(&row[lane * 4]);
    float4 a = *reinterpret_cast<const float4*>(&va[lane * 4]);
    float4 b = *reinterpret_cast<const float4*>(&vb[lane * 4]);
    s1 = h.x * a.x + h.y * a.y + h.z * a.z + h.w * a.w;
    s2 = h.x * b.x + h.y * b.y + h.z * b.z + h.w * b.w;
  } else {
    float2 h = *reinterpret_cast<const float2*>(&row[lane * 2]);
    float2 a = *reinterpret_cast<const float2*>(&va[lane * 2]);
    float2 b = *reinterpret_cast<const float2*>(&vb[lane * 2]);
    s1 = h.x * a.x + h.y * a.y;
    s2 = h.x * b.x + h.y * b.y;
  }
#pragma unroll
  for (int d = 32; d; d >>= 1) {
    s1 += __shfl_down(s1, d);
    s2 += __shfl_down(s2, d);
  }
  if (lane == 0) {
    f1[i] = s1;
    f2[i] = s2;
  }
}

// s = sigmoid(a*(f1[src]+f2[dst])); att<-s; m[src] = max(m, s) (s>0 so int-bits OK)
__global__ void k_edge_s(const float* __restrict__ aval, const int* __restrict__ src,
                         const int* __restrict__ dst, const float* __restrict__ f1,
                         const float* __restrict__ f2, float* __restrict__ att,
                         float* __restrict__ m, int E) {
  int e = blockIdx.x * blockDim.x + threadIdx.x;
  if (e >= E) return;
  float x = aval[e] * (f1[src[e]] + f2[dst[e]]);
  float s = 1.0f / (1.0f + __expf(-x));
  att[e] = s;
  atomicMax((int*)&m[src[e]], __float_as_int(s));
}

// att <- exp(att - m[src]); denom[src] += att
__global__ void k_edge_exp(const int* __restrict__ src, const float* __restrict__ m,
                           float* __restrict__ att, float* __restrict__ denom,
                           int E) {
  int e = blockIdx.x * blockDim.x + threadIdx.x;
  if (e >= E) return;
  float ev = __expf(att[e] - m[src[e]]);
  att[e] = ev;
  atomicAdd(&denom[src[e]], ev);
}

// out[i, :D] (row stride ldo) = (sum att_e * Hw[dst_e]) / denom[i]
template <int D>
__global__ __launch_bounds__(256) void k_agg(const float* __restrict__ Hw,
                                             const float* __restrict__ att,
                                             const int* __restrict__ row_ptr,
                                             const int* __restrict__ eid,
                                             const int* __restrict__ dst,
                                             const float* __restrict__ denom,
                                             float* __restrict__ out, int M,
                                             int ldo) {
  int wid = threadIdx.x >> 6, lane = threadIdx.x & 63;
  int i = blockIdx.x * 4 + wid;
  if (i >= M) return;
  int p0 = __builtin_amdgcn_readfirstlane(row_ptr[i]);
  int p1 = __builtin_amdgcn_readfirstlane(row_ptr[i + 1]);
  if (D == 256) {
    float4 acc = {0.f, 0.f, 0.f, 0.f};
    for (int p = p0; p < p1; ++p) {
      int e = eid[p];
      float w = att[e];
      int j = dst[e];
      float4 h = *reinterpret_cast<const float4*>(&Hw[(size_t)j * 256 + lane * 4]);
      acc.x = fmaf(w, h.x, acc.x);
      acc.y = fmaf(w, h.y, acc.y);
      acc.z = fmaf(w, h.z, acc.z);
      acc.w = fmaf(w, h.w, acc.w);
    }
    float inv = (p1 > p0) ? 1.0f / denom[i] : 0.0f;
    float4 o = {acc.x * inv, acc.y * inv, acc.z * inv, acc.w * inv};
    *reinterpret_cast<float4*>(&out[(size_t)i * ldo + lane * 4]) = o;
  } else {
    float2 acc = {0.f, 0.f};
    for (int p = p0; p < p1; ++p) {
      int e = eid[p];
      float w = att[e];
      int j = dst[e];
      float2 h = *reinterpret_cast<const float2*>(&Hw[(size_t)j * 128 + lane * 2]);
      acc.x = fmaf(w, h.x, acc.x);
      acc.y = fmaf(w, h.y, acc.y);
    }
    float inv = (p1 > p0) ? 1.0f / denom[i] : 0.0f;
    float2 o = {acc.x * inv, acc.y * inv};
    *reinterpret_cast<float2*>(&out[(size_t)i * ldo + lane * 2]) = o;
  }
}

// ------------------------------ launcher -----------------------------------

extern "C" void kernel_launch(void* const* d_in, const int* in_sizes, int n_in,
                              void* d_out, int out_size, void* d_ws, size_t ws_size,
                              hipStream_t stream) {
  (void)n_in;
  (void)out_size;
  const float* x = (const float*)d_in[0];
  const float* aval = (const float*)d_in[1];
  const float* W0 = (const float*)d_in[2];
  const float* W1 = (const float*)d_in[3];
  const float* v00 = (const float*)d_in[4];
  const float* v01 = (const float*)d_in[5];
  const float* v10 = (const float*)d_in[6];
  const float* v11 = (const float*)d_in[7];
  const float* fme = (const float*)d_in[8];
  const float* pW = (const float*)d_in[9];
  const float* pb = (const float*)d_in[10];
  const int* esrc = (const int*)d_in[11];
  const int* edst = (const int*)d_in[12];
  const int N = in_sizes[0] / 512;
  const int E = in_sizes[1];
  float* out = (float*)d_out;

  char* w = (char*)d_ws;
  size_t off = 0;
  auto alloc = [&](size_t bytes) -> char* {
    char* p = w + off;
    off += (bytes + 255) & ~(size_t)255;
    return p;
  };
  float* Hw0 = (float*)alloc((size_t)N * 256 * 4); // also: Hw1 (L2, Nx128)
  float* H1 = (float*)alloc((size_t)N * 256 * 4);  // also: Hcat (Nx192)
  float* f1 = (float*)alloc((size_t)N * 4);
  float* f2 = (float*)alloc((size_t)N * 4);
  float* mbuf = (float*)alloc((size_t)N * 4);
  float* dnm = (float*)alloc((size_t)N * 4);
  float* att = (float*)alloc((size_t)E * 4);
  int* cnt = (int*)alloc((size_t)N * 4);
  int* rp = (int*)alloc((size_t)(N + 1) * 4);
  int* cur = (int*)alloc((size_t)N * 4);
  int* eid = (int*)alloc((size_t)E * 4);
  int* part = (int*)alloc(4096);
  if (off > ws_size) return; // workspace too small: fail loudly via validation

  float* Hw1 = Hw0;  // N x 128 (Hw0 dead after L1 agg)
  float* Hcat = H1;  // N x 192 [H2 | nfm] (H1 dead after L2 GEMM)

  const int TPB = 256;
  int egrid = (E + TPB - 1) / TPB;
  int ngrid4 = (N + 3) / 4;
  int P = (N + 511) / 512;

  // ---- CSR build ----
  hipMemsetAsync(cnt, 0, (size_t)N * 4, stream);
  k_hist<<<egrid, TPB, 0, stream>>>(esrc, cnt, E);
  k_scan1<<<P, TPB, 0, stream>>>(cnt, rp, part, N);
  k_scan2<<<1, TPB, 0, stream>>>(part, P);
  k_scan3<<<(N + TPB) / TPB, TPB, 0, stream>>>(rp, cur, part, N, E);
  k_scatter<<<egrid, TPB, 0, stream>>>(esrc, cur, eid, E);

  // ---- Layer 1 (d=256) ----
  {
    dim3 g((N + 127) / 128, 256 / 64);
    k_gemm<128, 64, 16><<<g, TPB, 0, stream>>>(x, W0, Hw0, N, 256, 512);
  }
  k_fvec<256><<<ngrid4, TPB, 0, stream>>>(Hw0, v00, v01, f1, f2, N);
  hipMemsetAsync(mbuf, 0, (size_t)N * 4, stream);
  hipMemsetAsync(dnm, 0, (size_t)N * 4, stream);
  k_edge_s<<<egrid, TPB, 0, stream>>>(aval, esrc, edst, f1, f2, att, mbuf, E);
  k_edge_exp<<<egrid, TPB, 0, stream>>>(esrc, mbuf, att, dnm, E);
  k_agg<256><<<ngrid4, TPB, 0, stream>>>(Hw0, att, rp, eid, edst, dnm, H1, N, 256);

  // ---- Layer 2 (d=128) ----
  {
    dim3 g((N + 127) / 128, 128 / 64);
    k_gemm<128, 64, 16><<<g, TPB, 0, stream>>>(H1, W1, Hw1, N, 128, 256);
  }
  // H1 is dead from here on; its buffer becomes Hcat.
  // NFM -> Hcat[:, 128:192]
  k_nfm<<<(N + 127) / 128, TPB, 0, stream>>>(x, fme, Hcat + 128, N, 512, 192);
  k_fvec<128><<<ngrid4, TPB, 0, stream>>>(Hw1, v10, v11, f1, f2, N);
  hipMemsetAsync(mbuf, 0, (size_t)N * 4, stream);
  hipMemsetAsync(dnm, 0, (size_t)N * 4, stream);
  k_edge_s<<<egrid, TPB, 0, stream>>>(aval, esrc, edst, f1, f2, att, mbuf, E);
  k_edge_exp<<<egrid, TPB, 0, stream>>>(esrc, mbuf, att, dnm, E);
  // agg -> Hcat[:, 0:128]
  k_agg<128><<<ngrid4, TPB, 0, stream>>>(Hw1, att, rp, eid, edst, dnm, Hcat, N, 192);

  // ---- projection: out = Hcat @ pW + pb ----
  {
    dim3 g((N + 127) / 128, 1);
    k_gemm_bias<128, 64, 16><<<g, TPB, 0, stream>>>(Hcat, pW, pb, out, N, 64, 192);
  }
}

// Round 10
// 2771.380 us; speedup vs baseline: 1.2327x; 1.0367x over previous
//
#include <hip/hip_runtime.h>

// ---------------------------------------------------------------------------
// GAT(2 layers) + NFM + projection for MI355X.
// Pipeline:
//   CSR build (hist -> scan -> scatter)            [once per call]
//   L1: GEMM x@W0 -> fvec -> cvt(bf16) -> edge softmax -> agg(bf16 gather)
//   L2: GEMM H1@W1 -> fvec -> cvt(bf16) -> edge softmax -> agg -> Hcat[:,0:128]
//   NFM dual-GEMM on x -> Hcat[:, 128:192]
//   proj GEMM: Hcat[N,192] @ P[192,64] + b -> out
// R5: k_proj shuffle version latency-bound (627us) -> tiled GEMM.      [-540us]
// R7: k_agg memory-bound (503us, 4.2TB/s, 2.12GB HBM, occ 80%, VALU 4%)
//     -> gather Hw in bf16 (att math stays fp32).  Buffers: H1 aliases
//     dead fp32 Hw0; bf16 copies live in their own 51MB buffer.
// ---------------------------------------------------------------------------

__device__ __forceinline__ int wave_prefix_incl(int v) {
  int lane = threadIdx.x & 63;
#pragma unroll
  for (int d = 1; d < 64; d <<= 1) {
    int n = __shfl_up(v, d);
    if (lane >= d) v += n;
  }
  return v;
}

__device__ __forceinline__ unsigned short f2bf(float f) {  // RNE
  unsigned int x = __float_as_uint(f);
  x += 0x7fffu + ((x >> 16) & 1u);
  return (unsigned short)(x >> 16);
}
__device__ __forceinline__ float bf2f(unsigned short u) {
  return __uint_as_float(((unsigned int)u) << 16);
}

// ------------------------------ CSR build ---------------------------------

__global__ void k_hist(const int* __restrict__ src, int* __restrict__ cnt, int E) {
  int e = blockIdx.x * blockDim.x + threadIdx.x;
  if (e < E) atomicAdd(&cnt[src[e]], 1);
}

__global__ void k_scan1(const int* __restrict__ cnt, int* __restrict__ row_ptr,
                        int* __restrict__ partials, int N) {
  int t = threadIdx.x;
  int base = blockIdx.x * 512 + t * 2;
  int e0 = (base < N) ? cnt[base] : 0;
  int e1 = (base + 1 < N) ? cnt[base + 1] : 0;
  int v = e0 + e1;
  int lane = t & 63, wid = t >> 6;
  int incl = wave_prefix_incl(v);
  __shared__ int wsum[4];
  if (lane == 63) wsum[wid] = incl;
  __syncthreads();
  int off = 0;
#pragma unroll
  for (int i = 0; i < 4; ++i)
    if (i < wid) off += wsum[i];
  incl += off;
  int excl = incl - v;
  if (base < N) row_ptr[base] = excl;
  if (base + 1 < N) row_ptr[base + 1] = excl + e0;
  if (t == 255) partials[blockIdx.x] = incl;
}

__global__ void k_scan2(int* partials, int P) {
  int t = threadIdx.x;
  int v = (t < P) ? partials[t] : 0;
  int lane = t & 63, wid = t >> 6;
  int incl = wave_prefix_incl(v);
  __shared__ int wsum[4];
  if (lane == 63) wsum[wid] = incl;
  __syncthreads();
  int off = 0;
#pragma unroll
  for (int i = 0; i < 4; ++i)
    if (i < wid) off += wsum[i];
  incl += off;
  if (t < P) partials[t] = incl - v; // exclusive
}

__global__ void k_scan3(int* __restrict__ row_ptr, int* __restrict__ cursor,
                        const int* __restrict__ partials, int N, int E) {
  int i = blockIdx.x * blockDim.x + threadIdx.x;
  if (i < N) {
    int v = row_ptr[i] + partials[i >> 9];
    row_ptr[i] = v;
    cursor[i] = v;
  }
  if (i == 0) row_ptr[N] = E;
}

__global__ void k_scatter(const int* __restrict__ src, int* __restrict__ cursor,
                          int* __restrict__ eid, int E) {
  int e = blockIdx.x * blockDim.x + threadIdx.x;
  if (e < E) {
    int p = atomicAdd(&cursor[src[e]], 1);
    eid[p] = e;
  }
}

// ------------------------------ fp32 GEMM ---------------------------------
// C[M,N] = A[M,K] @ B[K,N].  BM=128 BN=64 BK=16, 256 thr, 8x4 micro-tile.

template <int BM, int BN, int BK>
__global__ __launch_bounds__(256) void k_gemm(const float* __restrict__ A,
                                              const float* __restrict__ B,
                                              float* __restrict__ C, int M, int N,
                                              int K) {
  __shared__ float As[BK][BM];
  __shared__ float Bs[BK][BN];
  int t = threadIdx.x;
  int bm0 = blockIdx.x * BM, bn0 = blockIdx.y * BN;
  int tr = t >> 4, tc = t & 15;
  int row0 = tr * 8, col0 = tc * 4;
  float acc[8][4] = {};
  for (int k0 = 0; k0 < K; k0 += BK) {
#pragma unroll
    for (int i = 0; i < 2; ++i) {
      int s = t + i * 256;
      int ar = s >> 2, akq = (s & 3) * 4;
      int grow = bm0 + ar;
      if (grow >= M) grow = M - 1;
      const float4 av =
          *reinterpret_cast<const float4*>(&A[(size_t)grow * K + k0 + akq]);
      As[akq + 0][ar] = av.x;
      As[akq + 1][ar] = av.y;
      As[akq + 2][ar] = av.z;
      As[akq + 3][ar] = av.w;
    }
    {
      int br = t >> 4, bc = (t & 15) * 4;
      const float4 bv =
          *reinterpret_cast<const float4*>(&B[(size_t)(k0 + br) * N + bn0 + bc]);
      *reinterpret_cast<float4*>(&Bs[br][bc]) = bv;
    }
    __syncthreads();
#pragma unroll
    for (int k = 0; k < BK; ++k) {
      float a0[8], b0[4];
      *reinterpret_cast<float4*>(&a0[0]) =
          *reinterpret_cast<const float4*>(&As[k][row0]);
      *reinterpret_cast<float4*>(&a0[4]) =
          *reinterpret_cast<const float4*>(&As[k][row0 + 4]);
      *reinterpret_cast<float4*>(&b0[0]) =
          *reinterpret_cast<const float4*>(&Bs[k][col0]);
#pragma unroll
      for (int i = 0; i < 8; ++i)
#pragma unroll
        for (int j = 0; j < 4; ++j) acc[i][j] = fmaf(a0[i], b0[j], acc[i][j]);
    }
    __syncthreads();
  }
#pragma unroll
  for (int i = 0; i < 8; ++i) {
    int grow = bm0 + row0 + i;
    if (grow < M) {
      float4 v = {acc[i][0], acc[i][1], acc[i][2], acc[i][3]};
      *reinterpret_cast<float4*>(&C[(size_t)grow * N + bn0 + col0]) = v;
    }
  }
}

// k_gemm + bias epilogue (projection).
template <int BM, int BN, int BK>
__global__ __launch_bounds__(256) void k_gemm_bias(const float* __restrict__ A,
                                                   const float* __restrict__ B,
                                                   const float* __restrict__ bias,
                                                   float* __restrict__ C, int M,
                                                   int N, int K) {
  __shared__ float As[BK][BM];
  __shared__ float Bs[BK][BN];
  int t = threadIdx.x;
  int bm0 = blockIdx.x * BM, bn0 = blockIdx.y * BN;
  int tr = t >> 4, tc = t & 15;
  int row0 = tr * 8, col0 = tc * 4;
  float acc[8][4] = {};
  for (int k0 = 0; k0 < K; k0 += BK) {
#pragma unroll
    for (int i = 0; i < 2; ++i) {
      int s = t + i * 256;
      int ar = s >> 2, akq = (s & 3) * 4;
      int grow = bm0 + ar;
      if (grow >= M) grow = M - 1;
      const float4 av =
          *reinterpret_cast<const float4*>(&A[(size_t)grow * K + k0 + akq]);
      As[akq + 0][ar] = av.x;
      As[akq + 1][ar] = av.y;
      As[akq + 2][ar] = av.z;
      As[akq + 3][ar] = av.w;
    }
    {
      int br = t >> 4, bc = (t & 15) * 4;
      const float4 bv =
          *reinterpret_cast<const float4*>(&B[(size_t)(k0 + br) * N + bn0 + bc]);
      *reinterpret_cast<float4*>(&Bs[br][bc]) = bv;
    }
    __syncthreads();
#pragma unroll
    for (int k = 0; k < BK; ++k) {
      float a0[8], b0[4];
      *reinterpret_cast<float4*>(&a0[0]) =
          *reinterpret_cast<const float4*>(&As[k][row0]);
      *reinterpret_cast<float4*>(&a0[4]) =
          *reinterpret_cast<const float4*>(&As[k][row0 + 4]);
      *reinterpret_cast<float4*>(&b0[0]) =
          *reinterpret_cast<const float4*>(&Bs[k][col0]);
#pragma unroll
      for (int i = 0; i < 8; ++i)
#pragma unroll
        for (int j = 0; j < 4; ++j) acc[i][j] = fmaf(a0[i], b0[j], acc[i][j]);
    }
    __syncthreads();
  }
  const float4 bv = *reinterpret_cast<const float4*>(&bias[bn0 + col0]);
#pragma unroll
  for (int i = 0; i < 8; ++i) {
    int grow = bm0 + row0 + i;
    if (grow < M) {
      float4 v = {acc[i][0] + bv.x, acc[i][1] + bv.y, acc[i][2] + bv.z,
                  acc[i][3] + bv.w};
      *reinterpret_cast<float4*>(&C[(size_t)grow * N + bn0 + col0]) = v;
    }
  }
}

// NFM: out[i, col] (row stride ldo) = 0.5*((X@Emb)^2 - X@Emb^2).  Emb [K,64].
__global__ __launch_bounds__(256) void k_nfm(const float* __restrict__ X,
                                             const float* __restrict__ Emb,
                                             float* __restrict__ out, int M,
                                             int K, int ldo) {
  const int BM = 128, BN = 64, BK = 16;
  __shared__ float As[BK][BM];
  __shared__ float Bs[BK][BN];
  int t = threadIdx.x;
  int bm0 = blockIdx.x * BM;
  int tr = t >> 4, tc = t & 15;
  int row0 = tr * 8, col0 = tc * 4;
  float accS[8][4] = {}, accQ[8][4] = {};
  for (int k0 = 0; k0 < K; k0 += BK) {
#pragma unroll
    for (int i = 0; i < 2; ++i) {
      int s = t + i * 256;
      int ar = s >> 2, akq = (s & 3) * 4;
      int grow = bm0 + ar;
      if (grow >= M) grow = M - 1;
      const float4 av =
          *reinterpret_cast<const float4*>(&X[(size_t)grow * K + k0 + akq]);
      As[akq + 0][ar] = av.x;
      As[akq + 1][ar] = av.y;
      As[akq + 2][ar] = av.z;
      As[akq + 3][ar] = av.w;
    }
    {
      int br = t >> 4, bc = (t & 15) * 4;
      const float4 bv =
          *reinterpret_cast<const float4*>(&Emb[(size_t)(k0 + br) * BN + bc]);
      *reinterpret_cast<float4*>(&Bs[br][bc]) = bv;
    }
    __syncthreads();
#pragma unroll
    for (int k = 0; k < BK; ++k) {
      float a0[8], b0[4], bq[4];
      *reinterpret_cast<float4*>(&a0[0]) =
          *reinterpret_cast<const float4*>(&As[k][row0]);
      *reinterpret_cast<float4*>(&a0[4]) =
          *reinterpret_cast<const float4*>(&As[k][row0 + 4]);
      *reinterpret_cast<float4*>(&b0[0]) =
          *reinterpret_cast<const float4*>(&Bs[k][col0]);
#pragma unroll
      for (int j = 0; j < 4; ++j) bq[j] = b0[j] * b0[j];
#pragma unroll
      for (int i = 0; i < 8; ++i)
#pragma unroll
        for (int j = 0; j < 4; ++j) {
          accS[i][j] = fmaf(a0[i], b0[j], accS[i][j]);
          accQ[i][j] = fmaf(a0[i], bq[j], accQ[i][j]);
        }
    }
    __syncthreads();
  }
#pragma unroll
  for (int i = 0; i < 8; ++i) {
    int grow = bm0 + row0 + i;
    if (grow < M) {
      float4 v;
      v.x = 0.5f * (accS[i][0] * accS[i][0] - accQ[i][0]);
      v.y = 0.5f * (accS[i][1] * accS[i][1] - accQ[i][1]);
      v.z = 0.5f * (accS[i][2] * accS[i][2] - accQ[i][2]);
      v.w = 0.5f * (accS[i][3] * accS[i][3] - accQ[i][3]);
      *reinterpret_cast<float4*>(&out[(size_t)grow * ldo + col0]) = v;
    }
  }
}

// --------------------------- fp32 -> bf16 cast -----------------------------
// total must be a multiple of 8 (N*256, N*128 both are).
__global__ __launch_bounds__(256) void k_cvt_bf16(const float* __restrict__ in,
                                                  unsigned short* __restrict__ out,
                                                  long total) {
  long base = ((long)blockIdx.x * blockDim.x + threadIdx.x) * 8;
  if (base >= total) return;
  float4 a = *reinterpret_cast<const float4*>(&in[base]);
  float4 b = *reinterpret_cast<const float4*>(&in[base + 4]);
  ushort4 lo = {f2bf(a.x), f2bf(a.y), f2bf(a.z), f2bf(a.w)};
  ushort4 hi = {f2bf(b.x), f2bf(b.y), f2bf(b.z), f2bf(b.w)};
  *reinterpret_cast<ushort4*>(&out[base]) = lo;
  *reinterpret_cast<ushort4*>(&out[base + 4]) = hi;
}

// ------------------------- GAT edge machinery ------------------------------

// f1 = Hw @ va, f2 = Hw @ vb, one wave per node (fp32 Hw, exact logits)
template <int D>
__global__ __launch_bounds__(256) void k_fvec(const float* __restrict__ Hw,
                                              const float* __restrict__ va,
                                              const float* __restrict__ vb,
                                              float* __restrict__ f1,
                                              float* __restrict__ f2, int M) {
  int wid = threadIdx.x >> 6, lane = threadIdx.x & 63;
  int i = blockIdx.x * 4 + wid;
  if (i >= M) return;
  const float* row = Hw + (size_t)i * D;
  float s1, s2;
  if (D == 256) {
    float4 h = *reinterpret_cast<const float4*>(&row[lane * 4]);
    float4 a = *reinterpret_cast<const float4*>(&va[lane * 4]);
    float4 b = *reinterpret_cast<const float4*>(&vb[lane * 4]);
    s1 = h.x * a.x + h.y * a.y + h.z * a.z + h.w * a.w;
    s2 = h.x * b.x + h.y * b.y + h.z * b.z + h.w * b.w;
  } else {
    float2 h = *reinterpret_cast<const float2*>(&row[lane * 2]);
    float2 a = *reinterpret_cast<const float2*>(&va[lane * 2]);
    float2 b = *reinterpret_cast<const float2*>(&vb[lane * 2]);
    s1 = h.x * a.x + h.y * a.y;
    s2 = h.x * b.x + h.y * b.y;
  }
#pragma unroll
  for (int d = 32; d; d >>= 1) {
    s1 += __shfl_down(s1, d);
    s2 += __shfl_down(s2, d);
  }
  if (lane == 0) {
    f1[i] = s1;
    f2[i] = s2;
  }
}

// s = sigmoid(a*(f1[src]+f2[dst])); att<-s; m[src] = max(m, s)
__global__ void k_edge_s(const float* __restrict__ aval, const int* __restrict__ src,
                         const int* __restrict__ dst, const float* __restrict__ f1,
                         const float* __restrict__ f2, float* __restrict__ att,
                         float* __restrict__ m, int E) {
  int e = blockIdx.x * blockDim.x + threadIdx.x;
  if (e >= E) return;
  float x = aval[e] * (f1[src[e]] + f2[dst[e]]);
  float s = 1.0f / (1.0f + __expf(-x));
  att[e] = s;
  atomicMax((int*)&m[src[e]], __float_as_int(s));
}

// att <- exp(att - m[src]); denom[src] += att
__global__ void k_edge_exp(const int* __restrict__ src, const float* __restrict__ m,
                           float* __restrict__ att, float* __restrict__ denom,
                           int E) {
  int e = blockIdx.x * blockDim.x + threadIdx.x;
  if (e >= E) return;
  float ev = __expf(att[e] - m[src[e]]);
  att[e] = ev;
  atomicAdd(&denom[src[e]], ev);
}

// out[i, :D] (row stride ldo, fp32) = (sum att_e * Hwb[dst_e]) / denom[i]
// Hwb is bf16; accumulation fp32. R7: halves gather bytes vs fp32 Hw.
template <int D>
__global__ __launch_bounds__(256) void k_agg(const unsigned short* __restrict__ Hwb,
                                             const float* __restrict__ att,
                                             const int* __restrict__ row_ptr,
                                             const int* __restrict__ eid,
                                             const int* __restrict__ dst,
                                             const float* __restrict__ denom,
                                             float* __restrict__ out, int M,
                                             int ldo) {
  int wid = threadIdx.x >> 6, lane = threadIdx.x & 63;
  int i = blockIdx.x * 4 + wid;
  if (i >= M) return;
  int p0 = __builtin_amdgcn_readfirstlane(row_ptr[i]);
  int p1 = __builtin_amdgcn_readfirstlane(row_ptr[i + 1]);
  if (D == 256) {
    // 4 bf16 per lane (8B): 64 lanes cover the 256-wide row.
    float4 acc = {0.f, 0.f, 0.f, 0.f};
    for (int p = p0; p < p1; ++p) {
      int e = eid[p];
      float w = att[e];
      int j = dst[e];
      ushort4 hv =
          *reinterpret_cast<const ushort4*>(&Hwb[(size_t)j * 256 + lane * 4]);
      acc.x = fmaf(w, bf2f(hv.x), acc.x);
      acc.y = fmaf(w, bf2f(hv.y), acc.y);
      acc.z = fmaf(w, bf2f(hv.z), acc.z);
      acc.w = fmaf(w, bf2f(hv.w), acc.w);
    }
    float inv = (p1 > p0) ? 1.0f / denom[i] : 0.0f;
    float4 o = {acc.x * inv, acc.y * inv, acc.z * inv, acc.w * inv};
    *reinterpret_cast<float4*>(&out[(size_t)i * ldo + lane * 4]) = o;
  } else {
    // 2 bf16 per lane (4B): 64 lanes cover the 128-wide row.
    float2 acc = {0.f, 0.f};
    for (int p = p0; p < p1; ++p) {
      int e = eid[p];
      float w = att[e];
      int j = dst[e];
      unsigned int hv =
          *reinterpret_cast<const unsigned int*>(&Hwb[(size_t)j * 128 + lane * 2]);
      acc.x = fmaf(w, bf2f((unsigned short)(hv & 0xffffu)), acc.x);
      acc.y = fmaf(w, bf2f((unsigned short)(hv >> 16)), acc.y);
    }
    float inv = (p1 > p0) ? 1.0f / denom[i] : 0.0f;
    float2 o = {acc.x * inv, acc.y * inv};
    *reinterpret_cast<float2*>(&out[(size_t)i * ldo + lane * 2]) = o;
  }
}

// ------------------------------ launcher -----------------------------------

extern "C" void kernel_launch(void* const* d_in, const int* in_sizes, int n_in,
                              void* d_out, int out_size, void* d_ws, size_t ws_size,
                              hipStream_t stream) {
  (void)n_in;
  (void)out_size;
  const float* x = (const float*)d_in[0];
  const float* aval = (const float*)d_in[1];
  const float* W0 = (const float*)d_in[2];
  const float* W1 = (const float*)d_in[3];
  const float* v00 = (const float*)d_in[4];
  const float* v01 = (const float*)d_in[5];
  const float* v10 = (const float*)d_in[6];
  const float* v11 = (const float*)d_in[7];
  const float* fme = (const float*)d_in[8];
  const float* pW = (const float*)d_in[9];
  const float* pb = (const float*)d_in[10];
  const int* esrc = (const int*)d_in[11];
  const int* edst = (const int*)d_in[12];
  const int N = in_sizes[0] / 512;
  const int E = in_sizes[1];
  float* out = (float*)d_out;

  char* w = (char*)d_ws;
  size_t off = 0;
  auto alloc = [&](size_t bytes) -> char* {
    char* p = w + off;
    off += (bytes + 255) & ~(size_t)255;
    return p;
  };
  // bufA fp32 Nx256: Hw0 -> (after cvt) H1 -> (after L2 GEMM) Hcat(Nx192)
  float* bufA = (float*)alloc((size_t)N * 256 * 4);
  // bufB bf16 Nx256: Hwb0, later Hwb1 (Nx128)
  unsigned short* bufB = (unsigned short*)alloc((size_t)N * 256 * 2);
  // bufC fp32 Nx128: Hw1 (L2 GEMM output; fvec + cvt read it)
  float* bufC = (float*)alloc((size_t)N * 128 * 4);
  float* f1 = (float*)alloc((size_t)N * 4);
  float* f2 = (float*)alloc((size_t)N * 4);
  float* mbuf = (float*)alloc((size_t)N * 4);
  float* dnm = (float*)alloc((size_t)N * 4);
  float* att = (float*)alloc((size_t)E * 4);
  int* cnt = (int*)alloc((size_t)N * 4);
  int* rp = (int*)alloc((size_t)(N + 1) * 4);
  int* cur = (int*)alloc((size_t)N * 4);
  int* eid = (int*)alloc((size_t)E * 4);
  int* part = (int*)alloc(4096);
  if (off > ws_size) return; // workspace too small: fail loudly via validation

  float* Hw0 = bufA;
  unsigned short* Hwb0 = bufB;
  float* H1 = bufA;   // alias: Hw0 fp32 dead after fvec+cvt
  float* Hw1 = bufC;
  unsigned short* Hwb1 = bufB;  // alias: Hwb0 dead after L1 agg
  float* Hcat = bufA; // alias: H1 dead after L2 GEMM (Nx192)

  const int TPB = 256;
  int egrid = (E + TPB - 1) / TPB;
  int ngrid4 = (N + 3) / 4;
  int P = (N + 511) / 512;

  // ---- CSR build ----
  hipMemsetAsync(cnt, 0, (size_t)N * 4, stream);
  k_hist<<<egrid, TPB, 0, stream>>>(esrc, cnt, E);
  k_scan1<<<P, TPB, 0, stream>>>(cnt, rp, part, N);
  k_scan2<<<1, TPB, 0, stream>>>(part, P);
  k_scan3<<<(N + TPB) / TPB, TPB, 0, stream>>>(rp, cur, part, N, E);
  k_scatter<<<egrid, TPB, 0, stream>>>(esrc, cur, eid, E);

  // ---- Layer 1 (d=256) ----
  {
    dim3 g((N + 127) / 128, 256 / 64);
    k_gemm<128, 64, 16><<<g, TPB, 0, stream>>>(x, W0, Hw0, N, 256, 512);
  }
  k_fvec<256><<<ngrid4, TPB, 0, stream>>>(Hw0, v00, v01, f1, f2, N);
  {
    long total = (long)N * 256;
    int g = (int)((total / 8 + TPB - 1) / TPB);
    k_cvt_bf16<<<g, TPB, 0, stream>>>(Hw0, Hwb0, total);
  }
  hipMemsetAsync(mbuf, 0, (size_t)N * 4, stream);
  hipMemsetAsync(dnm, 0, (size_t)N * 4, stream);
  k_edge_s<<<egrid, TPB, 0, stream>>>(aval, esrc, edst, f1, f2, att, mbuf, E);
  k_edge_exp<<<egrid, TPB, 0, stream>>>(esrc, mbuf, att, dnm, E);
  // writes H1 (=bufA, fp32 Hw0 dead), reads Hwb0 (=bufB)
  k_agg<256><<<ngrid4, TPB, 0, stream>>>(Hwb0, att, rp, eid, edst, dnm, H1, N, 256);

  // ---- Layer 2 (d=128) ----
  {
    dim3 g((N + 127) / 128, 128 / 64);
    k_gemm<128, 64, 16><<<g, TPB, 0, stream>>>(H1, W1, Hw1, N, 128, 256);
  }
  // H1 (bufA) dead from here; becomes Hcat.
  k_nfm<<<(N + 127) / 128, TPB, 0, stream>>>(x, fme, Hcat + 128, N, 512, 192);
  k_fvec<128><<<ngrid4, TPB, 0, stream>>>(Hw1, v10, v11, f1, f2, N);
  {
    long total = (long)N * 128;
    int g = (int)((total / 8 + TPB - 1) / TPB);
    k_cvt_bf16<<<g, TPB, 0, stream>>>(Hw1, Hwb1, total);
  }
  hipMemsetAsync(mbuf, 0, (size_t)N * 4, stream);
  hipMemsetAsync(dnm, 0, (size_t)N * 4, stream);
  k_edge_s<<<egrid, TPB, 0, stream>>>(aval, esrc, edst, f1, f2, att, mbuf, E);
  k_edge_exp<<<egrid, TPB, 0, stream>>>(esrc, mbuf, att, dnm, E);
  // writes Hcat[:, 0:128] (=bufA), reads Hwb1 (=bufB)
  k_agg<128><<<ngrid4, TPB, 0, stream>>>(Hwb1, att, rp, eid, edst, dnm, Hcat, N, 192);

  // ---- projection: out = Hcat @ pW + pb ----
  {
    dim3 g((N + 127) / 128, 1);
    k_gemm_bias<128, 64, 16><<<g, TPB, 0, stream>>>(Hcat, pW, pb, out, N, 64, 192);
  }
}

// Round 11
// 2328.121 us; speedup vs baseline: 1.4674x; 1.1904x over previous
//
#include <hip/hip_runtime.h>

// ---------------------------------------------------------------------------
// GAT(2 layers) + NFM + projection for MI355X.
// Pipeline:
//   CSR build (hist -> scan -> scatter)            [once per call]
//   L1: GEMM x@W0 -> fvec -> cvt(bf16) -> k_edge(sig+exp+denom) -> agg
//   L2: GEMM H1@W1 -> fvec -> cvt(bf16) -> k_edge -> agg -> Hcat[:,0:128]
//   NFM dual-GEMM on x -> Hcat[:, 128:192]
//   proj GEMM: Hcat[N,192] @ P[192,64] + b -> out
// R5:  k_proj shuffle latency-bound (627us) -> tiled GEMM.           [-540us]
// R7:  k_agg mem-bound 4.2TB/s, 2.12GB -> bf16 gather (1.30GB).      [-170us]
// R10: bf16 gather dropped to 3.3TB/s (8B/lane loads). Fix: multi-edge
//      waves, 16B/lane (half-wave per edge at D=256, quarter-wave at
//      D=128, shfl_xor combine). Also drop segment-max pass: sigmoid
//      s in (0,1) so exp(s) is safe and the max shift cancels exactly;
//      edge softmax is now ONE pass (sigmoid+exp+atomicAdd denom).
// ---------------------------------------------------------------------------

__device__ __forceinline__ int wave_prefix_incl(int v) {
  int lane = threadIdx.x & 63;
#pragma unroll
  for (int d = 1; d < 64; d <<= 1) {
    int n = __shfl_up(v, d);
    if (lane >= d) v += n;
  }
  return v;
}

__device__ __forceinline__ unsigned short f2bf(float f) {  // RNE
  unsigned int x = __float_as_uint(f);
  x += 0x7fffu + ((x >> 16) & 1u);
  return (unsigned short)(x >> 16);
}

// ------------------------------ CSR build ---------------------------------

__global__ void k_hist(const int* __restrict__ src, int* __restrict__ cnt, int E) {
  int e = blockIdx.x * blockDim.x + threadIdx.x;
  if (e < E) atomicAdd(&cnt[src[e]], 1);
}

__global__ void k_scan1(const int* __restrict__ cnt, int* __restrict__ row_ptr,
                        int* __restrict__ partials, int N) {
  int t = threadIdx.x;
  int base = blockIdx.x * 512 + t * 2;
  int e0 = (base < N) ? cnt[base] : 0;
  int e1 = (base + 1 < N) ? cnt[base + 1] : 0;
  int v = e0 + e1;
  int lane = t & 63, wid = t >> 6;
  int incl = wave_prefix_incl(v);
  __shared__ int wsum[4];
  if (lane == 63) wsum[wid] = incl;
  __syncthreads();
  int off = 0;
#pragma unroll
  for (int i = 0; i < 4; ++i)
    if (i < wid) off += wsum[i];
  incl += off;
  int excl = incl - v;
  if (base < N) row_ptr[base] = excl;
  if (base + 1 < N) row_ptr[base + 1] = excl + e0;
  if (t == 255) partials[blockIdx.x] = incl;
}

__global__ void k_scan2(int* partials, int P) {
  int t = threadIdx.x;
  int v = (t < P) ? partials[t] : 0;
  int lane = t & 63, wid = t >> 6;
  int incl = wave_prefix_incl(v);
  __shared__ int wsum[4];
  if (lane == 63) wsum[wid] = incl;
  __syncthreads();
  int off = 0;
#pragma unroll
  for (int i = 0; i < 4; ++i)
    if (i < wid) off += wsum[i];
  incl += off;
  if (t < P) partials[t] = incl - v; // exclusive
}

__global__ void k_scan3(int* __restrict__ row_ptr, int* __restrict__ cursor,
                        const int* __restrict__ partials, int N, int E) {
  int i = blockIdx.x * blockDim.x + threadIdx.x;
  if (i < N) {
    int v = row_ptr[i] + partials[i >> 9];
    row_ptr[i] = v;
    cursor[i] = v;
  }
  if (i == 0) row_ptr[N] = E;
}

__global__ void k_scatter(const int* __restrict__ src, int* __restrict__ cursor,
                          int* __restrict__ eid, int E) {
  int e = blockIdx.x * blockDim.x + threadIdx.x;
  if (e < E) {
    int p = atomicAdd(&cursor[src[e]], 1);
    eid[p] = e;
  }
}

// ------------------------------ fp32 GEMM ---------------------------------
// C[M,N] = A[M,K] @ B[K,N].  BM=128 BN=64 BK=16, 256 thr, 8x4 micro-tile.

template <int BM, int BN, int BK>
__global__ __launch_bounds__(256) void k_gemm(const float* __restrict__ A,
                                              const float* __restrict__ B,
                                              float* __restrict__ C, int M, int N,
                                              int K) {
  __shared__ float As[BK][BM];
  __shared__ float Bs[BK][BN];
  int t = threadIdx.x;
  int bm0 = blockIdx.x * BM, bn0 = blockIdx.y * BN;
  int tr = t >> 4, tc = t & 15;
  int row0 = tr * 8, col0 = tc * 4;
  float acc[8][4] = {};
  for (int k0 = 0; k0 < K; k0 += BK) {
#pragma unroll
    for (int i = 0; i < 2; ++i) {
      int s = t + i * 256;
      int ar = s >> 2, akq = (s & 3) * 4;
      int grow = bm0 + ar;
      if (grow >= M) grow = M - 1;
      const float4 av =
          *reinterpret_cast<const float4*>(&A[(size_t)grow * K + k0 + akq]);
      As[akq + 0][ar] = av.x;
      As[akq + 1][ar] = av.y;
      As[akq + 2][ar] = av.z;
      As[akq + 3][ar] = av.w;
    }
    {
      int br = t >> 4, bc = (t & 15) * 4;
      const float4 bv =
          *reinterpret_cast<const float4*>(&B[(size_t)(k0 + br) * N + bn0 + bc]);
      *reinterpret_cast<float4*>(&Bs[br][bc]) = bv;
    }
    __syncthreads();
#pragma unroll
    for (int k = 0; k < BK; ++k) {
      float a0[8], b0[4];
      *reinterpret_cast<float4*>(&a0[0]) =
          *reinterpret_cast<const float4*>(&As[k][row0]);
      *reinterpret_cast<float4*>(&a0[4]) =
          *reinterpret_cast<const float4*>(&As[k][row0 + 4]);
      *reinterpret_cast<float4*>(&b0[0]) =
          *reinterpret_cast<const float4*>(&Bs[k][col0]);
#pragma unroll
      for (int i = 0; i < 8; ++i)
#pragma unroll
        for (int j = 0; j < 4; ++j) acc[i][j] = fmaf(a0[i], b0[j], acc[i][j]);
    }
    __syncthreads();
  }
#pragma unroll
  for (int i = 0; i < 8; ++i) {
    int grow = bm0 + row0 + i;
    if (grow < M) {
      float4 v = {acc[i][0], acc[i][1], acc[i][2], acc[i][3]};
      *reinterpret_cast<float4*>(&C[(size_t)grow * N + bn0 + col0]) = v;
    }
  }
}

// k_gemm + bias epilogue (projection).
template <int BM, int BN, int BK>
__global__ __launch_bounds__(256) void k_gemm_bias(const float* __restrict__ A,
                                                   const float* __restrict__ B,
                                                   const float* __restrict__ bias,
                                                   float* __restrict__ C, int M,
                                                   int N, int K) {
  __shared__ float As[BK][BM];
  __shared__ float Bs[BK][BN];
  int t = threadIdx.x;
  int bm0 = blockIdx.x * BM, bn0 = blockIdx.y * BN;
  int tr = t >> 4, tc = t & 15;
  int row0 = tr * 8, col0 = tc * 4;
  float acc[8][4] = {};
  for (int k0 = 0; k0 < K; k0 += BK) {
#pragma unroll
    for (int i = 0; i < 2; ++i) {
      int s = t + i * 256;
      int ar = s >> 2, akq = (s & 3) * 4;
      int grow = bm0 + ar;
      if (grow >= M) grow = M - 1;
      const float4 av =
          *reinterpret_cast<const float4*>(&A[(size_t)grow * K + k0 + akq]);
      As[akq + 0][ar] = av.x;
      As[akq + 1][ar] = av.y;
      As[akq + 2][ar] = av.z;
      As[akq + 3][ar] = av.w;
    }
    {
      int br = t >> 4, bc = (t & 15) * 4;
      const float4 bv =
          *reinterpret_cast<const float4*>(&B[(size_t)(k0 + br) * N + bn0 + bc]);
      *reinterpret_cast<float4*>(&Bs[br][bc]) = bv;
    }
    __syncthreads();
#pragma unroll
    for (int k = 0; k < BK; ++k) {
      float a0[8], b0[4];
      *reinterpret_cast<float4*>(&a0[0]) =
          *reinterpret_cast<const float4*>(&As[k][row0]);
      *reinterpret_cast<float4*>(&a0[4]) =
          *reinterpret_cast<const float4*>(&As[k][row0 + 4]);
      *reinterpret_cast<float4*>(&b0[0]) =
          *reinterpret_cast<const float4*>(&Bs[k][col0]);
#pragma unroll
      for (int i = 0; i < 8; ++i)
#pragma unroll
        for (int j = 0; j < 4; ++j) acc[i][j] = fmaf(a0[i], b0[j], acc[i][j]);
    }
    __syncthreads();
  }
  const float4 bv = *reinterpret_cast<const float4*>(&bias[bn0 + col0]);
#pragma unroll
  for (int i = 0; i < 8; ++i) {
    int grow = bm0 + row0 + i;
    if (grow < M) {
      float4 v = {acc[i][0] + bv.x, acc[i][1] + bv.y, acc[i][2] + bv.z,
                  acc[i][3] + bv.w};
      *reinterpret_cast<float4*>(&C[(size_t)grow * N + bn0 + col0]) = v;
    }
  }
}

// NFM: out[i, col] (row stride ldo) = 0.5*((X@Emb)^2 - X@Emb^2).  Emb [K,64].
__global__ __launch_bounds__(256) void k_nfm(const float* __restrict__ X,
                                             const float* __restrict__ Emb,
                                             float* __restrict__ out, int M,
                                             int K, int ldo) {
  const int BM = 128, BN = 64, BK = 16;
  __shared__ float As[BK][BM];
  __shared__ float Bs[BK][BN];
  int t = threadIdx.x;
  int bm0 = blockIdx.x * BM;
  int tr = t >> 4, tc = t & 15;
  int row0 = tr * 8, col0 = tc * 4;
  float accS[8][4] = {}, accQ[8][4] = {};
  for (int k0 = 0; k0 < K; k0 += BK) {
#pragma unroll
    for (int i = 0; i < 2; ++i) {
      int s = t + i * 256;
      int ar = s >> 2, akq = (s & 3) * 4;
      int grow = bm0 + ar;
      if (grow >= M) grow = M - 1;
      const float4 av =
          *reinterpret_cast<const float4*>(&X[(size_t)grow * K + k0 + akq]);
      As[akq + 0][ar] = av.x;
      As[akq + 1][ar] = av.y;
      As[akq + 2][ar] = av.z;
      As[akq + 3][ar] = av.w;
    }
    {
      int br = t >> 4, bc = (t & 15) * 4;
      const float4 bv =
          *reinterpret_cast<const float4*>(&Emb[(size_t)(k0 + br) * BN + bc]);
      *reinterpret_cast<float4*>(&Bs[br][bc]) = bv;
    }
    __syncthreads();
#pragma unroll
    for (int k = 0; k < BK; ++k) {
      float a0[8], b0[4], bq[4];
      *reinterpret_cast<float4*>(&a0[0]) =
          *reinterpret_cast<const float4*>(&As[k][row0]);
      *reinterpret_cast<float4*>(&a0[4]) =
          *reinterpret_cast<const float4*>(&As[k][row0 + 4]);
      *reinterpret_cast<float4*>(&b0[0]) =
          *reinterpret_cast<const float4*>(&Bs[k][col0]);
#pragma unroll
      for (int j = 0; j < 4; ++j) bq[j] = b0[j] * b0[j];
#pragma unroll
      for (int i = 0; i < 8; ++i)
#pragma unroll
        for (int j = 0; j < 4; ++j) {
          accS[i][j] = fmaf(a0[i], b0[j], accS[i][j]);
          accQ[i][j] = fmaf(a0[i], bq[j], accQ[i][j]);
        }
    }
    __syncthreads();
  }
#pragma unroll
  for (int i = 0; i < 8; ++i) {
    int grow = bm0 + row0 + i;
    if (grow < M) {
      float4 v;
      v.x = 0.5f * (accS[i][0] * accS[i][0] - accQ[i][0]);
      v.y = 0.5f * (accS[i][1] * accS[i][1] - accQ[i][1]);
      v.z = 0.5f * (accS[i][2] * accS[i][2] - accQ[i][2]);
      v.w = 0.5f * (accS[i][3] * accS[i][3] - accQ[i][3]);
      *reinterpret_cast<float4*>(&out[(size_t)grow * ldo + col0]) = v;
    }
  }
}

// --------------------------- fp32 -> bf16 cast -----------------------------
__global__ __launch_bounds__(256) void k_cvt_bf16(const float* __restrict__ in,
                                                  unsigned short* __restrict__ out,
                                                  long total) {
  long base = ((long)blockIdx.x * blockDim.x + threadIdx.x) * 8;
  if (base >= total) return;
  float4 a = *reinterpret_cast<const float4*>(&in[base]);
  float4 b = *reinterpret_cast<const float4*>(&in[base + 4]);
  ushort4 lo = {f2bf(a.x), f2bf(a.y), f2bf(a.z), f2bf(a.w)};
  ushort4 hi = {f2bf(b.x), f2bf(b.y), f2bf(b.z), f2bf(b.w)};
  *reinterpret_cast<ushort4*>(&out[base]) = lo;
  *reinterpret_cast<ushort4*>(&out[base + 4]) = hi;
}

// ------------------------- GAT edge machinery ------------------------------

// f1 = Hw @ va, f2 = Hw @ vb, one wave per node (fp32 Hw, exact logits)
template <int D>
__global__ __launch_bounds__(256) void k_fvec(const float* __restrict__ Hw,
                                              const float* __restrict__ va,
                                              const float* __restrict__ vb,
                                              float* __restrict__ f1,
                                              float* __restrict__ f2, int M) {
  int wid = threadIdx.x >> 6, lane = threadIdx.x & 63;
  int i = blockIdx.x * 4 + wid;
  if (i >= M) return;
  const float* row = Hw + (size_t)i * D;
  float s1, s2;
  if (D == 256) {
    float4 h = *reinterpret_cast<const float4*>(&row[lane * 4]);
    float4 a = *reinterpret_cast<const float4*>(&va[lane * 4]);
    float4 b = *reinterpret_cast<const float4*>(&vb[lane * 4]);
    s1 = h.x * a.x + h.y * a.y + h.z * a.z + h.w * a.w;
    s2 = h.x * b.x + h.y * b.y + h.z * b.z + h.w * b.w;
  } else {
    float2 h = *reinterpret_cast<const float2*>(&row[lane * 2]);
    float2 a = *reinterpret_cast<const float2*>(&va[lane * 2]);
    float2 b = *reinterpret_cast<const float2*>(&vb[lane * 2]);
    s1 = h.x * a.x + h.y * a.y;
    s2 = h.x * b.x + h.y * b.y;
  }
#pragma unroll
  for (int d = 32; d; d >>= 1) {
    s1 += __shfl_down(s1, d);
    s2 += __shfl_down(s2, d);
  }
  if (lane == 0) {
    f1[i] = s1;
    f2[i] = s2;
  }
}

// Fused edge softmax pass (R10): s = sigmoid(a*(f1[src]+f2[dst])) in (0,1),
// so exp(s) cannot overflow and the segment-max shift cancels exactly.
// att[e] = exp(s); denom[src] += exp(s).  One pass instead of two + memset.
__global__ void k_edge(const float* __restrict__ aval, const int* __restrict__ src,
                       const int* __restrict__ dst, const float* __restrict__ f1,
                       const float* __restrict__ f2, float* __restrict__ att,
                       float* __restrict__ denom, int E) {
  int e = blockIdx.x * blockDim.x + threadIdx.x;
  if (e >= E) return;
  float x = aval[e] * (f1[src[e]] + f2[dst[e]]);
  float s = 1.0f / (1.0f + __expf(-x));
  float ev = __expf(s);
  att[e] = ev;
  atomicAdd(&denom[src[e]], ev);
}

// R10 multi-edge agg: restore 16B/lane loads.
// D=256: 2 half-waves x 32 lanes, each half owns edges p0+half, p0+half+2,...
//        lane loads 8 bf16 (16B); halves combined via shfl_xor(32).
// D=128: 4 quarter-waves x 16 lanes; combine via shfl_xor(32) then (16).
template <int D>
__global__ __launch_bounds__(256) void k_agg(const unsigned short* __restrict__ Hwb,
                                             const float* __restrict__ att,
                                             const int* __restrict__ row_ptr,
                                             const int* __restrict__ eid,
                                             const int* __restrict__ dst,
                                             const float* __restrict__ denom,
                                             float* __restrict__ out, int M,
                                             int ldo) {
  int wid = threadIdx.x >> 6, lane = threadIdx.x & 63;
  int i = blockIdx.x * 4 + wid;
  if (i >= M) return;
  int p0 = __builtin_amdgcn_readfirstlane(row_ptr[i]);
  int p1 = __builtin_amdgcn_readfirstlane(row_ptr[i + 1]);
  float acc[8] = {};
  if (D == 256) {
    int half = lane >> 5, q = lane & 31;
    for (int p = p0 + half; p < p1; p += 2) {
      int e = eid[p];
      float w = att[e];
      int j = dst[e];
      uint4 hv =
          *reinterpret_cast<const uint4*>(&Hwb[(size_t)j * 256 + q * 8]);
#pragma unroll
      for (int c = 0; c < 4; ++c) {
        unsigned int u = (&hv.x)[c];
        acc[2 * c + 0] = fmaf(w, __uint_as_float(u << 16), acc[2 * c + 0]);
        acc[2 * c + 1] = fmaf(w, __uint_as_float(u & 0xffff0000u), acc[2 * c + 1]);
      }
    }
#pragma unroll
    for (int c = 0; c < 8; ++c) acc[c] += __shfl_xor(acc[c], 32);
    if (half == 0) {
      float inv = (p1 > p0) ? 1.0f / denom[i] : 0.0f;
      float4 lo = {acc[0] * inv, acc[1] * inv, acc[2] * inv, acc[3] * inv};
      float4 hi = {acc[4] * inv, acc[5] * inv, acc[6] * inv, acc[7] * inv};
      *reinterpret_cast<float4*>(&out[(size_t)i * ldo + q * 8]) = lo;
      *reinterpret_cast<float4*>(&out[(size_t)i * ldo + q * 8 + 4]) = hi;
    }
  } else {
    int quarter = lane >> 4, q = lane & 15;
    for (int p = p0 + quarter; p < p1; p += 4) {
      int e = eid[p];
      float w = att[e];
      int j = dst[e];
      uint4 hv =
          *reinterpret_cast<const uint4*>(&Hwb[(size_t)j * 128 + q * 8]);
#pragma unroll
      for (int c = 0; c < 4; ++c) {
        unsigned int u = (&hv.x)[c];
        acc[2 * c + 0] = fmaf(w, __uint_as_float(u << 16), acc[2 * c + 0]);
        acc[2 * c + 1] = fmaf(w, __uint_as_float(u & 0xffff0000u), acc[2 * c + 1]);
      }
    }
#pragma unroll
    for (int c = 0; c < 8; ++c) acc[c] += __shfl_xor(acc[c], 32);
#pragma unroll
    for (int c = 0; c < 8; ++c) acc[c] += __shfl_xor(acc[c], 16);
    if (quarter == 0) {
      float inv = (p1 > p0) ? 1.0f / denom[i] : 0.0f;
      float4 lo = {acc[0] * inv, acc[1] * inv, acc[2] * inv, acc[3] * inv};
      float4 hi = {acc[4] * inv, acc[5] * inv, acc[6] * inv, acc[7] * inv};
      *reinterpret_cast<float4*>(&out[(size_t)i * ldo + q * 8]) = lo;
      *reinterpret_cast<float4*>(&out[(size_t)i * ldo + q * 8 + 4]) = hi;
    }
  }
}

// ------------------------------ launcher -----------------------------------

extern "C" void kernel_launch(void* const* d_in, const int* in_sizes, int n_in,
                              void* d_out, int out_size, void* d_ws, size_t ws_size,
                              hipStream_t stream) {
  (void)n_in;
  (void)out_size;
  const float* x = (const float*)d_in[0];
  const float* aval = (const float*)d_in[1];
  const float* W0 = (const float*)d_in[2];
  const float* W1 = (const float*)d_in[3];
  const float* v00 = (const float*)d_in[4];
  const float* v01 = (const float*)d_in[5];
  const float* v10 = (const float*)d_in[6];
  const float* v11 = (const float*)d_in[7];
  const float* fme = (const float*)d_in[8];
  const float* pW = (const float*)d_in[9];
  const float* pb = (const float*)d_in[10];
  const int* esrc = (const int*)d_in[11];
  const int* edst = (const int*)d_in[12];
  const int N = in_sizes[0] / 512;
  const int E = in_sizes[1];
  float* out = (float*)d_out;

  char* w = (char*)d_ws;
  size_t off = 0;
  auto alloc = [&](size_t bytes) -> char* {
    char* p = w + off;
    off += (bytes + 255) & ~(size_t)255;
    return p;
  };
  // bufA fp32 Nx256: Hw0 -> (after cvt) H1 -> (after L2 GEMM) Hcat(Nx192)
  float* bufA = (float*)alloc((size_t)N * 256 * 4);
  // bufB bf16 Nx256: Hwb0, later Hwb1 (Nx128)
  unsigned short* bufB = (unsigned short*)alloc((size_t)N * 256 * 2);
  // bufC fp32 Nx128: Hw1 (L2 GEMM output; fvec + cvt read it)
  float* bufC = (float*)alloc((size_t)N * 128 * 4);
  float* f1 = (float*)alloc((size_t)N * 4);
  float* f2 = (float*)alloc((size_t)N * 4);
  float* dnm = (float*)alloc((size_t)N * 4);
  float* att = (float*)alloc((size_t)E * 4);
  int* cnt = (int*)alloc((size_t)N * 4);
  int* rp = (int*)alloc((size_t)(N + 1) * 4);
  int* cur = (int*)alloc((size_t)N * 4);
  int* eid = (int*)alloc((size_t)E * 4);
  int* part = (int*)alloc(4096);
  if (off > ws_size) return; // workspace too small: fail loudly via validation

  float* Hw0 = bufA;
  unsigned short* Hwb0 = bufB;
  float* H1 = bufA;   // alias: Hw0 fp32 dead after fvec+cvt
  float* Hw1 = bufC;
  unsigned short* Hwb1 = bufB;  // alias: Hwb0 dead after L1 agg
  float* Hcat = bufA; // alias: H1 dead after L2 GEMM (Nx192)

  const int TPB = 256;
  int egrid = (E + TPB - 1) / TPB;
  int ngrid4 = (N + 3) / 4;
  int P = (N + 511) / 512;

  // ---- CSR build ----
  hipMemsetAsync(cnt, 0, (size_t)N * 4, stream);
  k_hist<<<egrid, TPB, 0, stream>>>(esrc, cnt, E);
  k_scan1<<<P, TPB, 0, stream>>>(cnt, rp, part, N);
  k_scan2<<<1, TPB, 0, stream>>>(part, P);
  k_scan3<<<(N + TPB) / TPB, TPB, 0, stream>>>(rp, cur, part, N, E);
  k_scatter<<<egrid, TPB, 0, stream>>>(esrc, cur, eid, E);

  // ---- Layer 1 (d=256) ----
  {
    dim3 g((N + 127) / 128, 256 / 64);
    k_gemm<128, 64, 16><<<g, TPB, 0, stream>>>(x, W0, Hw0, N, 256, 512);
  }
  k_fvec<256><<<ngrid4, TPB, 0, stream>>>(Hw0, v00, v01, f1, f2, N);
  {
    long total = (long)N * 256;
    int g = (int)((total / 8 + TPB - 1) / TPB);
    k_cvt_bf16<<<g, TPB, 0, stream>>>(Hw0, Hwb0, total);
  }
  hipMemsetAsync(dnm, 0, (size_t)N * 4, stream);
  k_edge<<<egrid, TPB, 0, stream>>>(aval, esrc, edst, f1, f2, att, dnm, E);
  // writes H1 (=bufA, fp32 Hw0 dead), reads Hwb0 (=bufB)
  k_agg<256><<<ngrid4, TPB, 0, stream>>>(Hwb0, att, rp, eid, edst, dnm, H1, N, 256);

  // ---- Layer 2 (d=128) ----
  {
    dim3 g((N + 127) / 128, 128 / 64);
    k_gemm<128, 64, 16><<<g, TPB, 0, stream>>>(H1, W1, Hw1, N, 128, 256);
  }
  // H1 (bufA) dead from here; becomes Hcat.
  k_nfm<<<(N + 127) / 128, TPB, 0, stream>>>(x, fme, Hcat + 128, N, 512, 192);
  k_fvec<128><<<ngrid4, TPB, 0, stream>>>(Hw1, v10, v11, f1, f2, N);
  {
    long total = (long)N * 128;
    int g = (int)((total / 8 + TPB - 1) / TPB);
    k_cvt_bf16<<<g, TPB, 0, stream>>>(Hw1, Hwb1, total);
  }
  hipMemsetAsync(dnm, 0, (size_t)N * 4, stream);
  k_edge<<<egrid, TPB, 0, stream>>>(aval, esrc, edst, f1, f2, att, dnm, E);
  // writes Hcat[:, 0:128] (=bufA), reads Hwb1 (=bufB)
  k_agg<128><<<ngrid4, TPB, 0, stream>>>(Hwb1, att, rp, eid, edst, dnm, Hcat, N, 192);

  // ---- projection: out = Hcat @ pW + pb ----
  {
    dim3 g((N + 127) / 128, 1);
    k_gemm_bias<128, 64, 16><<<g, TPB, 0, stream>>>(Hcat, pW, pb, out, N, 64, 192);
  }
}

// Round 12
// 2221.125 us; speedup vs baseline: 1.5380x; 1.0482x over previous
//
#include <hip/hip_runtime.h>

// ---------------------------------------------------------------------------
// GAT(2 layers) + NFM + projection for MI355X.
// Pipeline:
//   CSR build (hist -> scan -> scatter)            [once per call]
//   L1: GEMM_bf16fv x@W0 -> Hwb0(bf16) + f1/f2 (fused epilogue)
//       -> k_edge(sig+exp+denom) -> agg(16B/lane bf16 gather) -> H1
//   L2: GEMM_bf16fv H1@W1 -> Hwb1 + f1/f2 -> k_edge -> agg -> Hcat[:,0:128]
//   NFM dual-GEMM on x -> Hcat[:, 128:192]
//   proj GEMM: Hcat[N,192] @ P[192,64] + b -> out
// R5:  k_proj shuffle latency-bound (627us) -> tiled GEMM.           [-540us]
// R7:  k_agg 4.2TB/s 2.12GB -> bf16 gather (1.30GB).                 [-170us]
// R10: 16B/lane multi-edge agg + one-pass edge softmax (exp(s) safe,
//      max shift cancels since s=sigmoid in (0,1)).                  [-440us]
// R11: k_gemm VALU-bound 73TF (VALUBusy 66%, 1.9e7 LDS conflicts).
//      (a) pad As/Bs +4 (4-way staging conflict -> 2-way = free);
//      (b) GEMM emits bf16 directly + computes f1/f2 in epilogue from
//          fp32 acc (shfl-reduce + 4 atomics/row) -> k_cvt & k_fvec gone.
// ---------------------------------------------------------------------------

__device__ __forceinline__ int wave_prefix_incl(int v) {
  int lane = threadIdx.x & 63;
#pragma unroll
  for (int d = 1; d < 64; d <<= 1) {
    int n = __shfl_up(v, d);
    if (lane >= d) v += n;
  }
  return v;
}

__device__ __forceinline__ unsigned short f2bf(float f) {  // RNE
  unsigned int x = __float_as_uint(f);
  x += 0x7fffu + ((x >> 16) & 1u);
  return (unsigned short)(x >> 16);
}

// ------------------------------ CSR build ---------------------------------

__global__ void k_hist(const int* __restrict__ src, int* __restrict__ cnt, int E) {
  int e = blockIdx.x * blockDim.x + threadIdx.x;
  if (e < E) atomicAdd(&cnt[src[e]], 1);
}

__global__ void k_scan1(const int* __restrict__ cnt, int* __restrict__ row_ptr,
                        int* __restrict__ partials, int N) {
  int t = threadIdx.x;
  int base = blockIdx.x * 512 + t * 2;
  int e0 = (base < N) ? cnt[base] : 0;
  int e1 = (base + 1 < N) ? cnt[base + 1] : 0;
  int v = e0 + e1;
  int lane = t & 63, wid = t >> 6;
  int incl = wave_prefix_incl(v);
  __shared__ int wsum[4];
  if (lane == 63) wsum[wid] = incl;
  __syncthreads();
  int off = 0;
#pragma unroll
  for (int i = 0; i < 4; ++i)
    if (i < wid) off += wsum[i];
  incl += off;
  int excl = incl - v;
  if (base < N) row_ptr[base] = excl;
  if (base + 1 < N) row_ptr[base + 1] = excl + e0;
  if (t == 255) partials[blockIdx.x] = incl;
}

__global__ void k_scan2(int* partials, int P) {
  int t = threadIdx.x;
  int v = (t < P) ? partials[t] : 0;
  int lane = t & 63, wid = t >> 6;
  int incl = wave_prefix_incl(v);
  __shared__ int wsum[4];
  if (lane == 63) wsum[wid] = incl;
  __syncthreads();
  int off = 0;
#pragma unroll
  for (int i = 0; i < 4; ++i)
    if (i < wid) off += wsum[i];
  incl += off;
  if (t < P) partials[t] = incl - v; // exclusive
}

__global__ void k_scan3(int* __restrict__ row_ptr, int* __restrict__ cursor,
                        const int* __restrict__ partials, int N, int E) {
  int i = blockIdx.x * blockDim.x + threadIdx.x;
  if (i < N) {
    int v = row_ptr[i] + partials[i >> 9];
    row_ptr[i] = v;
    cursor[i] = v;
  }
  if (i == 0) row_ptr[N] = E;
}

__global__ void k_scatter(const int* __restrict__ src, int* __restrict__ cursor,
                          int* __restrict__ eid, int E) {
  int e = blockIdx.x * blockDim.x + threadIdx.x;
  if (e < E) {
    int p = atomicAdd(&cursor[src[e]], 1);
    eid[p] = e;
  }
}

// --------------- GEMM with bf16 output + fused f1/f2 epilogue --------------
// Cb[M,N](bf16) = A[M,K] @ B[K,N]; f1 += Cb_row . va, f2 += Cb_row . vb
// (computed from fp32 acc, so logits match the fp32-exact path).
// BM=128 BN=64 BK=16, 256 thr, 8x4 micro-tile. As/Bs padded +4 (R11).
template <int BM, int BN, int BK>
__global__ __launch_bounds__(256) void k_gemm_bf16_fv(
    const float* __restrict__ A, const float* __restrict__ B,
    const float* __restrict__ va, const float* __restrict__ vb,
    unsigned short* __restrict__ Cb, float* __restrict__ f1,
    float* __restrict__ f2, int M, int N, int K) {
  __shared__ float As[BK][BM + 4];
  __shared__ float Bs[BK][BN + 4];
  int t = threadIdx.x;
  int bm0 = blockIdx.x * BM, bn0 = blockIdx.y * BN;
  int tr = t >> 4, tc = t & 15;
  int row0 = tr * 8, col0 = tc * 4;
  float acc[8][4] = {};
  for (int k0 = 0; k0 < K; k0 += BK) {
#pragma unroll
    for (int i = 0; i < 2; ++i) {
      int s = t + i * 256;
      int ar = s >> 2, akq = (s & 3) * 4;
      int grow = bm0 + ar;
      if (grow >= M) grow = M - 1;
      const float4 av =
          *reinterpret_cast<const float4*>(&A[(size_t)grow * K + k0 + akq]);
      As[akq + 0][ar] = av.x;
      As[akq + 1][ar] = av.y;
      As[akq + 2][ar] = av.z;
      As[akq + 3][ar] = av.w;
    }
    {
      int br = t >> 4, bc = (t & 15) * 4;
      const float4 bv =
          *reinterpret_cast<const float4*>(&B[(size_t)(k0 + br) * N + bn0 + bc]);
      *reinterpret_cast<float4*>(&Bs[br][bc]) = bv;
    }
    __syncthreads();
#pragma unroll
    for (int k = 0; k < BK; ++k) {
      float a0[8], b0[4];
      *reinterpret_cast<float4*>(&a0[0]) =
          *reinterpret_cast<const float4*>(&As[k][row0]);
      *reinterpret_cast<float4*>(&a0[4]) =
          *reinterpret_cast<const float4*>(&As[k][row0 + 4]);
      *reinterpret_cast<float4*>(&b0[0]) =
          *reinterpret_cast<const float4*>(&Bs[k][col0]);
#pragma unroll
      for (int i = 0; i < 8; ++i)
#pragma unroll
        for (int j = 0; j < 4; ++j) acc[i][j] = fmaf(a0[i], b0[j], acc[i][j]);
    }
    __syncthreads();
  }
  const float4 va4 = *reinterpret_cast<const float4*>(&va[bn0 + col0]);
  const float4 vb4 = *reinterpret_cast<const float4*>(&vb[bn0 + col0]);
#pragma unroll
  for (int i = 0; i < 8; ++i) {
    int grow = bm0 + row0 + i;
    bool live = grow < M;
    if (live) {
      ushort4 o = {f2bf(acc[i][0]), f2bf(acc[i][1]), f2bf(acc[i][2]),
                   f2bf(acc[i][3])};
      *reinterpret_cast<ushort4*>(&Cb[(size_t)grow * N + bn0 + col0]) = o;
    }
    float p1 = acc[i][0] * va4.x + acc[i][1] * va4.y + acc[i][2] * va4.z +
               acc[i][3] * va4.w;
    float p2 = acc[i][0] * vb4.x + acc[i][1] * vb4.y + acc[i][2] * vb4.z +
               acc[i][3] * vb4.w;
    // reduce over the 16 tc lanes (xor masks stay inside the 16-lane group);
    // all lanes of a group share `grow`, so shfl participation is uniform.
#pragma unroll
    for (int d = 1; d < 16; d <<= 1) {
      p1 += __shfl_xor(p1, d);
      p2 += __shfl_xor(p2, d);
    }
    if (live && tc == 0) {
      atomicAdd(&f1[grow], p1);
      atomicAdd(&f2[grow], p2);
    }
  }
}

// fp32 GEMM + bias epilogue (projection).  As/Bs padded +4 (R11).
template <int BM, int BN, int BK>
__global__ __launch_bounds__(256) void k_gemm_bias(const float* __restrict__ A,
                                                   const float* __restrict__ B,
                                                   const float* __restrict__ bias,
                                                   float* __restrict__ C, int M,
                                                   int N, int K) {
  __shared__ float As[BK][BM + 4];
  __shared__ float Bs[BK][BN + 4];
  int t = threadIdx.x;
  int bm0 = blockIdx.x * BM, bn0 = blockIdx.y * BN;
  int tr = t >> 4, tc = t & 15;
  int row0 = tr * 8, col0 = tc * 4;
  float acc[8][4] = {};
  for (int k0 = 0; k0 < K; k0 += BK) {
#pragma unroll
    for (int i = 0; i < 2; ++i) {
      int s = t + i * 256;
      int ar = s >> 2, akq = (s & 3) * 4;
      int grow = bm0 + ar;
      if (grow >= M) grow = M - 1;
      const float4 av =
          *reinterpret_cast<const float4*>(&A[(size_t)grow * K + k0 + akq]);
      As[akq + 0][ar] = av.x;
      As[akq + 1][ar] = av.y;
      As[akq + 2][ar] = av.z;
      As[akq + 3][ar] = av.w;
    }
    {
      int br = t >> 4, bc = (t & 15) * 4;
      const float4 bv =
          *reinterpret_cast<const float4*>(&B[(size_t)(k0 + br) * N + bn0 + bc]);
      *reinterpret_cast<float4*>(&Bs[br][bc]) = bv;
    }
    __syncthreads();
#pragma unroll
    for (int k = 0; k < BK; ++k) {
      float a0[8], b0[4];
      *reinterpret_cast<float4*>(&a0[0]) =
          *reinterpret_cast<const float4*>(&As[k][row0]);
      *reinterpret_cast<float4*>(&a0[4]) =
          *reinterpret_cast<const float4*>(&As[k][row0 + 4]);
      *reinterpret_cast<float4*>(&b0[0]) =
          *reinterpret_cast<const float4*>(&Bs[k][col0]);
#pragma unroll
      for (int i = 0; i < 8; ++i)
#pragma unroll
        for (int j = 0; j < 4; ++j) acc[i][j] = fmaf(a0[i], b0[j], acc[i][j]);
    }
    __syncthreads();
  }
  const float4 bv = *reinterpret_cast<const float4*>(&bias[bn0 + col0]);
#pragma unroll
  for (int i = 0; i < 8; ++i) {
    int grow = bm0 + row0 + i;
    if (grow < M) {
      float4 v = {acc[i][0] + bv.x, acc[i][1] + bv.y, acc[i][2] + bv.z,
                  acc[i][3] + bv.w};
      *reinterpret_cast<float4*>(&C[(size_t)grow * N + bn0 + col0]) = v;
    }
  }
}

// NFM: out[i, col] (row stride ldo) = 0.5*((X@Emb)^2 - X@Emb^2).  Emb [K,64].
// As/Bs padded +4 (R11).
__global__ __launch_bounds__(256) void k_nfm(const float* __restrict__ X,
                                             const float* __restrict__ Emb,
                                             float* __restrict__ out, int M,
                                             int K, int ldo) {
  const int BM = 128, BN = 64, BK = 16;
  __shared__ float As[BK][BM + 4];
  __shared__ float Bs[BK][BN + 4];
  int t = threadIdx.x;
  int bm0 = blockIdx.x * BM;
  int tr = t >> 4, tc = t & 15;
  int row0 = tr * 8, col0 = tc * 4;
  float accS[8][4] = {}, accQ[8][4] = {};
  for (int k0 = 0; k0 < K; k0 += BK) {
#pragma unroll
    for (int i = 0; i < 2; ++i) {
      int s = t + i * 256;
      int ar = s >> 2, akq = (s & 3) * 4;
      int grow = bm0 + ar;
      if (grow >= M) grow = M - 1;
      const float4 av =
          *reinterpret_cast<const float4*>(&X[(size_t)grow * K + k0 + akq]);
      As[akq + 0][ar] = av.x;
      As[akq + 1][ar] = av.y;
      As[akq + 2][ar] = av.z;
      As[akq + 3][ar] = av.w;
    }
    {
      int br = t >> 4, bc = (t & 15) * 4;
      const float4 bv =
          *reinterpret_cast<const float4*>(&Emb[(size_t)(k0 + br) * BN + bc]);
      *reinterpret_cast<float4*>(&Bs[br][bc]) = bv;
    }
    __syncthreads();
#pragma unroll
    for (int k = 0; k < BK; ++k) {
      float a0[8], b0[4], bq[4];
      *reinterpret_cast<float4*>(&a0[0]) =
          *reinterpret_cast<const float4*>(&As[k][row0]);
      *reinterpret_cast<float4*>(&a0[4]) =
          *reinterpret_cast<const float4*>(&As[k][row0 + 4]);
      *reinterpret_cast<float4*>(&b0[0]) =
          *reinterpret_cast<const float4*>(&Bs[k][col0]);
#pragma unroll
      for (int j = 0; j < 4; ++j) bq[j] = b0[j] * b0[j];
#pragma unroll
      for (int i = 0; i < 8; ++i)
#pragma unroll
        for (int j = 0; j < 4; ++j) {
          accS[i][j] = fmaf(a0[i], b0[j], accS[i][j]);
          accQ[i][j] = fmaf(a0[i], bq[j], accQ[i][j]);
        }
    }
    __syncthreads();
  }
#pragma unroll
  for (int i = 0; i < 8; ++i) {
    int grow = bm0 + row0 + i;
    if (grow < M) {
      float4 v;
      v.x = 0.5f * (accS[i][0] * accS[i][0] - accQ[i][0]);
      v.y = 0.5f * (accS[i][1] * accS[i][1] - accQ[i][1]);
      v.z = 0.5f * (accS[i][2] * accS[i][2] - accQ[i][2]);
      v.w = 0.5f * (accS[i][3] * accS[i][3] - accQ[i][3]);
      *reinterpret_cast<float4*>(&out[(size_t)grow * ldo + col0]) = v;
    }
  }
}

// ------------------------- GAT edge machinery ------------------------------

// Fused edge softmax pass (R10): s = sigmoid(a*(f1[src]+f2[dst])) in (0,1),
// so exp(s) cannot overflow and the segment-max shift cancels exactly.
__global__ void k_edge(const float* __restrict__ aval, const int* __restrict__ src,
                       const int* __restrict__ dst, const float* __restrict__ f1,
                       const float* __restrict__ f2, float* __restrict__ att,
                       float* __restrict__ denom, int E) {
  int e = blockIdx.x * blockDim.x + threadIdx.x;
  if (e >= E) return;
  float x = aval[e] * (f1[src[e]] + f2[dst[e]]);
  float s = 1.0f / (1.0f + __expf(-x));
  float ev = __expf(s);
  att[e] = ev;
  atomicAdd(&denom[src[e]], ev);
}

// R10 multi-edge agg, 16B/lane loads.
// D=256: 2 half-waves x 32 lanes; D=128: 4 quarter-waves x 16 lanes.
template <int D>
__global__ __launch_bounds__(256) void k_agg(const unsigned short* __restrict__ Hwb,
                                             const float* __restrict__ att,
                                             const int* __restrict__ row_ptr,
                                             const int* __restrict__ eid,
                                             const int* __restrict__ dst,
                                             const float* __restrict__ denom,
                                             float* __restrict__ out, int M,
                                             int ldo) {
  int wid = threadIdx.x >> 6, lane = threadIdx.x & 63;
  int i = blockIdx.x * 4 + wid;
  if (i >= M) return;
  int p0 = __builtin_amdgcn_readfirstlane(row_ptr[i]);
  int p1 = __builtin_amdgcn_readfirstlane(row_ptr[i + 1]);
  float acc[8] = {};
  if (D == 256) {
    int half = lane >> 5, q = lane & 31;
    for (int p = p0 + half; p < p1; p += 2) {
      int e = eid[p];
      float w = att[e];
      int j = dst[e];
      uint4 hv =
          *reinterpret_cast<const uint4*>(&Hwb[(size_t)j * 256 + q * 8]);
#pragma unroll
      for (int c = 0; c < 4; ++c) {
        unsigned int u = (&hv.x)[c];
        acc[2 * c + 0] = fmaf(w, __uint_as_float(u << 16), acc[2 * c + 0]);
        acc[2 * c + 1] = fmaf(w, __uint_as_float(u & 0xffff0000u), acc[2 * c + 1]);
      }
    }
#pragma unroll
    for (int c = 0; c < 8; ++c) acc[c] += __shfl_xor(acc[c], 32);
    if (half == 0) {
      float inv = (p1 > p0) ? 1.0f / denom[i] : 0.0f;
      float4 lo = {acc[0] * inv, acc[1] * inv, acc[2] * inv, acc[3] * inv};
      float4 hi = {acc[4] * inv, acc[5] * inv, acc[6] * inv, acc[7] * inv};
      *reinterpret_cast<float4*>(&out[(size_t)i * ldo + q * 8]) = lo;
      *reinterpret_cast<float4*>(&out[(size_t)i * ldo + q * 8 + 4]) = hi;
    }
  } else {
    int quarter = lane >> 4, q = lane & 15;
    for (int p = p0 + quarter; p < p1; p += 4) {
      int e = eid[p];
      float w = att[e];
      int j = dst[e];
      uint4 hv =
          *reinterpret_cast<const uint4*>(&Hwb[(size_t)j * 128 + q * 8]);
#pragma unroll
      for (int c = 0; c < 4; ++c) {
        unsigned int u = (&hv.x)[c];
        acc[2 * c + 0] = fmaf(w, __uint_as_float(u << 16), acc[2 * c + 0]);
        acc[2 * c + 1] = fmaf(w, __uint_as_float(u & 0xffff0000u), acc[2 * c + 1]);
      }
    }
#pragma unroll
    for (int c = 0; c < 8; ++c) acc[c] += __shfl_xor(acc[c], 32);
#pragma unroll
    for (int c = 0; c < 8; ++c) acc[c] += __shfl_xor(acc[c], 16);
    if (quarter == 0) {
      float inv = (p1 > p0) ? 1.0f / denom[i] : 0.0f;
      float4 lo = {acc[0] * inv, acc[1] * inv, acc[2] * inv, acc[3] * inv};
      float4 hi = {acc[4] * inv, acc[5] * inv, acc[6] * inv, acc[7] * inv};
      *reinterpret_cast<float4*>(&out[(size_t)i * ldo + q * 8]) = lo;
      *reinterpret_cast<float4*>(&out[(size_t)i * ldo + q * 8 + 4]) = hi;
    }
  }
}

// ------------------------------ launcher -----------------------------------

extern "C" void kernel_launch(void* const* d_in, const int* in_sizes, int n_in,
                              void* d_out, int out_size, void* d_ws, size_t ws_size,
                              hipStream_t stream) {
  (void)n_in;
  (void)out_size;
  const float* x = (const float*)d_in[0];
  const float* aval = (const float*)d_in[1];
  const float* W0 = (const float*)d_in[2];
  const float* W1 = (const float*)d_in[3];
  const float* v00 = (const float*)d_in[4];
  const float* v01 = (const float*)d_in[5];
  const float* v10 = (const float*)d_in[6];
  const float* v11 = (const float*)d_in[7];
  const float* fme = (const float*)d_in[8];
  const float* pW = (const float*)d_in[9];
  const float* pb = (const float*)d_in[10];
  const int* esrc = (const int*)d_in[11];
  const int* edst = (const int*)d_in[12];
  const int N = in_sizes[0] / 512;
  const int E = in_sizes[1];
  float* out = (float*)d_out;

  char* w = (char*)d_ws;
  size_t off = 0;
  auto alloc = [&](size_t bytes) -> char* {
    char* p = w + off;
    off += (bytes + 255) & ~(size_t)255;
    return p;
  };
  // bufA fp32 Nx256: H1 (L1 agg out) -> (after L2 GEMM) Hcat(Nx192)
  float* bufA = (float*)alloc((size_t)N * 256 * 4);
  // bufB bf16 Nx256: Hwb0 (L1 GEMM out), later Hwb1 (Nx128, L2 GEMM out)
  unsigned short* bufB = (unsigned short*)alloc((size_t)N * 256 * 2);
  float* f1 = (float*)alloc((size_t)N * 4);
  float* f2 = (float*)alloc((size_t)N * 4);
  float* dnm = (float*)alloc((size_t)N * 4);
  float* att = (float*)alloc((size_t)E * 4);
  int* cnt = (int*)alloc((size_t)N * 4);
  int* rp = (int*)alloc((size_t)(N + 1) * 4);
  int* cur = (int*)alloc((size_t)N * 4);
  int* eid = (int*)alloc((size_t)E * 4);
  int* part = (int*)alloc(4096);
  if (off > ws_size) return; // workspace too small: fail loudly via validation

  unsigned short* Hwb0 = bufB;
  float* H1 = bufA;
  unsigned short* Hwb1 = bufB;  // alias: Hwb0 dead after L1 agg
  float* Hcat = bufA;           // alias: H1 dead after L2 GEMM (Nx192)

  const int TPB = 256;
  int egrid = (E + TPB - 1) / TPB;
  int ngrid4 = (N + 3) / 4;
  int P = (N + 511) / 512;

  // ---- CSR build ----
  hipMemsetAsync(cnt, 0, (size_t)N * 4, stream);
  k_hist<<<egrid, TPB, 0, stream>>>(esrc, cnt, E);
  k_scan1<<<P, TPB, 0, stream>>>(cnt, rp, part, N);
  k_scan2<<<1, TPB, 0, stream>>>(part, P);
  k_scan3<<<(N + TPB) / TPB, TPB, 0, stream>>>(rp, cur, part, N, E);
  k_scatter<<<egrid, TPB, 0, stream>>>(esrc, cur, eid, E);

  // ---- Layer 1 (d=256) ----
  hipMemsetAsync(f1, 0, (size_t)N * 4, stream);
  hipMemsetAsync(f2, 0, (size_t)N * 4, stream);
  hipMemsetAsync(dnm, 0, (size_t)N * 4, stream);
  {
    dim3 g((N + 127) / 128, 256 / 64);
    k_gemm_bf16_fv<128, 64, 16>
        <<<g, TPB, 0, stream>>>(x, W0, v00, v01, Hwb0, f1, f2, N, 256, 512);
  }
  k_edge<<<egrid, TPB, 0, stream>>>(aval, esrc, edst, f1, f2, att, dnm, E);
  // writes H1 (=bufA), reads Hwb0 (=bufB)
  k_agg<256><<<ngrid4, TPB, 0, stream>>>(Hwb0, att, rp, eid, edst, dnm, H1, N, 256);

  // ---- Layer 2 (d=128) ----
  hipMemsetAsync(f1, 0, (size_t)N * 4, stream);
  hipMemsetAsync(f2, 0, (size_t)N * 4, stream);
  hipMemsetAsync(dnm, 0, (size_t)N * 4, stream);
  {
    dim3 g((N + 127) / 128, 128 / 64);
    k_gemm_bf16_fv<128, 64, 16>
        <<<g, TPB, 0, stream>>>(H1, W1, v10, v11, Hwb1, f1, f2, N, 128, 256);
  }
  // H1 (bufA) dead from here; becomes Hcat.
  k_nfm<<<(N + 127) / 128, TPB, 0, stream>>>(x, fme, Hcat + 128, N, 512, 192);
  k_edge<<<egrid, TPB, 0, stream>>>(aval, esrc, edst, f1, f2, att, dnm, E);
  // writes Hcat[:, 0:128] (=bufA), reads Hwb1 (=bufB)
  k_agg<128><<<ngrid4, TPB, 0, stream>>>(Hwb1, att, rp, eid, edst, dnm, Hcat, N, 192);

  // ---- projection: out = Hcat @ pW + pb ----
  {
    dim3 g((N + 127) / 128, 1);
    k_gemm_bias<128, 64, 16><<<g, TPB, 0, stream>>>(Hcat, pW, pb, out, N, 64, 192);
  }
}